// Round 4
// baseline (23794.986 us; speedup 1.0000x reference)
//
#include <hip/hip_runtime.h>
#include <stdint.h>

// Problem constants
#define T_   512
#define B_   64
#define DIN  1024
#define HID  512
#define G3   1536     // 3*HID
#define NC   3072     // both dirs of gates
#define MROWS 32768   // T_*B_

typedef __bf16 bf16;
typedef __bf16 bf16x8 __attribute__((ext_vector_type(8)));
typedef float  f32x4  __attribute__((ext_vector_type(4)));

#define GLOBAL_AS __attribute__((address_space(1)))
#define LDS_AS    __attribute__((address_space(3)))

__device__ __forceinline__ uint16_t f2bf_bits(float x){
  union{float f; uint32_t u;} v; v.f = x;
  uint32_t u = v.u;
  u += 0x7FFFu + ((u >> 16) & 1u);   // round-to-nearest-even
  return (uint16_t)(u >> 16);
}
__device__ __forceinline__ float bf2f_bits(uint16_t h){
  union{uint32_t u; float f;} v; v.u = ((uint32_t)h) << 16;
  return v.f;
}
__device__ __forceinline__ float bfsel(uint32_t w, int hi){
  union{uint32_t u; float f;} v; v.u = hi ? (w & 0xffff0000u) : (w << 16);
  return v.f;
}
__device__ __forceinline__ float sig_f(float x){
  return 1.f/(1.f + __expf(-x));
}
__device__ __forceinline__ float tanh_f(float x){
  return 1.f - 2.f/(1.f + __expf(2.f*x));
}

// ---------------------------------------------------------------- converts
__global__ void k_conv_emb(const float* __restrict__ src, uint16_t* __restrict__ dst, long n8){
  long i = (long)blockIdx.x*blockDim.x + threadIdx.x;
  if(i >= n8) return;
  const float4* s = (const float4*)src;
  float4 a = s[i*2], b = s[i*2+1];
  uint32_t p0 = (uint32_t)f2bf_bits(a.x) | ((uint32_t)f2bf_bits(a.y) << 16);
  uint32_t p1 = (uint32_t)f2bf_bits(a.z) | ((uint32_t)f2bf_bits(a.w) << 16);
  uint32_t p2 = (uint32_t)f2bf_bits(b.x) | ((uint32_t)f2bf_bits(b.y) << 16);
  uint32_t p3 = (uint32_t)f2bf_bits(b.z) | ((uint32_t)f2bf_bits(b.w) << 16);
  ((uint4*)dst)[i] = make_uint4(p0,p1,p2,p3);
}

__global__ void k_conv_wcat(const float* __restrict__ wf, const float* __restrict__ wb, uint16_t* __restrict__ dst, int n){
  int i = blockIdx.x*256 + threadIdx.x;
  if(i >= n) return;
  float v = (i < G3*DIN) ? wf[i] : wb[i - G3*DIN];
  dst[i] = f2bf_bits(v);
}

__global__ void k_conv_awt(const float* __restrict__ aw, uint16_t* __restrict__ dst, int n){
  int i = blockIdx.x*256 + threadIdx.x;
  if(i >= n) return;
  int e = i >> 10, d = i & 1023;
  dst[i] = f2bf_bits(aw[d*1024 + e]);   // transpose: awT[e][d]
}

// ---------------------------------------------------------------- GEMM: xp = emb @ Wcat^T + bias
// OUTPUT TRANSPOSED: xp2[col][row], col in [0,3072), row in [0,32768)
__launch_bounds__(256)
__global__ void k_gemm_xp(const uint16_t* __restrict__ A, const uint16_t* __restrict__ Bw,
                          const float* __restrict__ bihf, const float* __restrict__ bihb,
                          uint16_t* __restrict__ C)
{
  __shared__ uint16_t lA[2][128*32];
  __shared__ uint16_t lB[2][128*32];
  const int K = 1024;
  int bn = blockIdx.x, bm = blockIdx.y;
  int tid = threadIdx.x;
  int lane = tid & 63, wid = tid >> 6;
  int wm = wid >> 1, wn = wid & 1;
  int rowBase = bm*128, colBase = bn*128;
  int rg = lane >> 4, rr = lane & 15;

  auto stage = [&](int buf, int kt){
    #pragma unroll
    for(int i=0;i<2;i++){
      int e = (i*256 + tid)*8;
      int r = e >> 5, c = e & 31;
      __builtin_amdgcn_global_load_lds((const GLOBAL_AS void*)(A + (size_t)(rowBase + r)*K + kt*32 + c),
                                       (LDS_AS void*)&lA[buf][e], 16, 0, 0);
    }
    #pragma unroll
    for(int i=0;i<2;i++){
      int e = (i*256 + tid)*8;
      int r = e >> 5, c = e & 31;
      __builtin_amdgcn_global_load_lds((const GLOBAL_AS void*)(Bw + (size_t)(colBase + r)*K + kt*32 + c),
                                       (LDS_AS void*)&lB[buf][e], 16, 0, 0);
    }
  };

  f32x4 acc[4][4];
  #pragma unroll
  for(int mi=0;mi<4;mi++)
    #pragma unroll
    for(int ni=0;ni<4;ni++) acc[mi][ni] = (f32x4){0.f,0.f,0.f,0.f};

  stage(0, 0);
  __syncthreads();
  for(int kt=0; kt<32; kt++){
    int buf = kt & 1;
    if(kt+1 < 32) stage(buf^1, kt+1);
    bf16x8 af[4], bfv[4];
    #pragma unroll
    for(int mi=0;mi<4;mi++)
      af[mi] = *(const bf16x8*)&lA[buf][(wm*64 + mi*16 + rr)*32 + rg*8];
    #pragma unroll
    for(int ni=0;ni<4;ni++)
      bfv[ni] = *(const bf16x8*)&lB[buf][(wn*64 + ni*16 + rr)*32 + rg*8];
    #pragma unroll
    for(int mi=0;mi<4;mi++)
      #pragma unroll
      for(int ni=0;ni<4;ni++)
        acc[mi][ni] = __builtin_amdgcn_mfma_f32_16x16x32_bf16(af[mi], bfv[ni], acc[mi][ni], 0,0,0);
    __syncthreads();
  }

  #pragma unroll
  for(int ni=0;ni<4;ni++){
    int col = colBase + wn*64 + ni*16 + rr;
    float bv = (col < G3) ? bihf[col] : bihb[col - G3];
    #pragma unroll
    for(int mi=0;mi<4;mi++){
      int row0 = rowBase + wm*64 + mi*16 + rg*4;
      uint32_t lo = (uint32_t)f2bf_bits(acc[mi][ni][0]+bv) | ((uint32_t)f2bf_bits(acc[mi][ni][1]+bv) << 16);
      uint32_t hi = (uint32_t)f2bf_bits(acc[mi][ni][2]+bv) | ((uint32_t)f2bf_bits(acc[mi][ni][3]+bv) << 16);
      *(uint2*)&C[(size_t)col*MROWS + row0] = make_uint2(lo, hi);
    }
  }
}

// ---------------------------------------------------------------- GEMM: attention, fused tanh + ctx_w dot
__launch_bounds__(256)
__global__ void k_gemm_att(const uint16_t* __restrict__ A, const uint16_t* __restrict__ Bw,
                           const float* __restrict__ attn_b, const float* __restrict__ ctx_w,
                           float* __restrict__ scores_raw)
{
  __shared__ uint16_t lA[2][128*32];
  __shared__ uint16_t lB[2][128*32];
  const int K = 1024;
  int bn = blockIdx.x, bm = blockIdx.y;
  int tid = threadIdx.x;
  int lane = tid & 63, wid = tid >> 6;
  int wm = wid >> 1, wn = wid & 1;
  int rowBase = bm*128, colBase = bn*128;
  int rg = lane >> 4, rr = lane & 15;

  auto stage = [&](int buf, int kt){
    #pragma unroll
    for(int i=0;i<2;i++){
      int e = (i*256 + tid)*8;
      int r = e >> 5, c = e & 31;
      __builtin_amdgcn_global_load_lds((const GLOBAL_AS void*)(A + (size_t)(rowBase + r)*K + kt*32 + c),
                                       (LDS_AS void*)&lA[buf][e], 16, 0, 0);
    }
    #pragma unroll
    for(int i=0;i<2;i++){
      int e = (i*256 + tid)*8;
      int r = e >> 5, c = e & 31;
      __builtin_amdgcn_global_load_lds((const GLOBAL_AS void*)(Bw + (size_t)(colBase + r)*K + kt*32 + c),
                                       (LDS_AS void*)&lB[buf][e], 16, 0, 0);
    }
  };

  f32x4 acc[4][4];
  #pragma unroll
  for(int mi=0;mi<4;mi++)
    #pragma unroll
    for(int ni=0;ni<4;ni++) acc[mi][ni] = (f32x4){0.f,0.f,0.f,0.f};

  stage(0, 0);
  __syncthreads();
  for(int kt=0; kt<32; kt++){
    int buf = kt & 1;
    if(kt+1 < 32) stage(buf^1, kt+1);
    bf16x8 af[4], bfv[4];
    #pragma unroll
    for(int mi=0;mi<4;mi++)
      af[mi] = *(const bf16x8*)&lA[buf][(wm*64 + mi*16 + rr)*32 + rg*8];
    #pragma unroll
    for(int ni=0;ni<4;ni++)
      bfv[ni] = *(const bf16x8*)&lB[buf][(wn*64 + ni*16 + rr)*32 + rg*8];
    #pragma unroll
    for(int mi=0;mi<4;mi++)
      #pragma unroll
      for(int ni=0;ni<4;ni++)
        acc[mi][ni] = __builtin_amdgcn_mfma_f32_16x16x32_bf16(af[mi], bfv[ni], acc[mi][ni], 0,0,0);
    __syncthreads();
  }

  float ab[4], cw[4];
  #pragma unroll
  for(int ni=0;ni<4;ni++){
    int col = colBase + wn*64 + ni*16 + rr;
    ab[ni] = attn_b[col];
    cw[ni] = ctx_w[col];
  }
  #pragma unroll
  for(int mi=0;mi<4;mi++){
    #pragma unroll
    for(int r=0;r<4;r++){
      float part = 0.f;
      #pragma unroll
      for(int ni=0;ni<4;ni++) part += tanhf(acc[mi][ni][r] + ab[ni]) * cw[ni];
      #pragma unroll
      for(int off=1; off<16; off<<=1) part += __shfl_xor(part, off);
      if(rr == 0){
        int row = rowBase + wm*64 + mi*16 + rg*4 + r;
        atomicAdd(&scores_raw[row], part);
      }
    }
  }
}

// ---------------------------------------------------------------- recurrence v4: W_hh in registers via 96 NAMED bf16x8 vars
// WG = (dir, 16 batch rows), 16 waves. Wave w owns gh cols {g*512 + w*32 + s*16 + rr}.
// h in LDS double-buffer, XOR-swizzled (col ^= (row&7)<<4), stride 512. One barrier/step.
#define DECLW(k) bf16x8 w0_##k, w1_##k, w2_##k, w3_##k, w4_##k, w5_##k;
#define LD1(tn,k) { float4 f0_ = *(const float4*)(wr##tn + (k)*32); \
                    float4 f1_ = *(const float4*)(wr##tn + (k)*32 + 4); \
                    union{uint32_t u[4]; bf16x8 v;} pk_; \
                    pk_.u[0] = (uint32_t)f2bf_bits(f0_.x) | ((uint32_t)f2bf_bits(f0_.y) << 16); \
                    pk_.u[1] = (uint32_t)f2bf_bits(f0_.z) | ((uint32_t)f2bf_bits(f0_.w) << 16); \
                    pk_.u[2] = (uint32_t)f2bf_bits(f1_.x) | ((uint32_t)f2bf_bits(f1_.y) << 16); \
                    pk_.u[3] = (uint32_t)f2bf_bits(f1_.z) | ((uint32_t)f2bf_bits(f1_.w) << 16); \
                    w##tn##_##k = pk_.v; }
#define LDK(k) LD1(0,k) LD1(1,k) LD1(2,k) LD1(3,k) LD1(4,k) LD1(5,k)
#define MK(k) { bf16x8 a_ = *(const bf16x8*)&hl[rdoff + (((k)*32 + rg8) ^ rswz)]; \
  acc0 = __builtin_amdgcn_mfma_f32_16x16x32_bf16(a_, w0_##k, acc0, 0,0,0); \
  acc1 = __builtin_amdgcn_mfma_f32_16x16x32_bf16(a_, w1_##k, acc1, 0,0,0); \
  acc2 = __builtin_amdgcn_mfma_f32_16x16x32_bf16(a_, w2_##k, acc2, 0,0,0); \
  acc3 = __builtin_amdgcn_mfma_f32_16x16x32_bf16(a_, w3_##k, acc3, 0,0,0); \
  acc4 = __builtin_amdgcn_mfma_f32_16x16x32_bf16(a_, w4_##k, acc4, 0,0,0); \
  acc5 = __builtin_amdgcn_mfma_f32_16x16x32_bf16(a_, w5_##k, acc5, 0,0,0); }

__launch_bounds__(1024)
__global__ void k_recur(const uint16_t* __restrict__ xp,   // transposed [3072][32768]
                        const float* __restrict__ whhf, const float* __restrict__ whhb,
                        const float* __restrict__ bhhf, const float* __restrict__ bhhb,
                        uint16_t* __restrict__ f_out)
{
  __shared__ uint16_t hl[2*16*512];   // 32 KB, swizzled

  int bid = blockIdx.x;
  int dir = bid & 1;
  int bg  = bid >> 1;            // 0..3
  int tid = threadIdx.x;
  int lane = tid & 63, w = tid >> 6;      // 16 waves
  int rg = lane >> 4, rr = lane & 15;
  int rg8 = rg*8;
  int rswz = (rr & 7) << 4;
  int rbase = rg*4;              // C rows rbase..rbase+3
  int cb = w*32 + rr;            // h-col base (s adds 16)

  const float* whh = dir ? whhb : whhf;
  const float* bhh = dir ? bhhb : bhhf;

  // W fragment row pointers (tn = g*2+s)
  const float* wr0 = whh + ((size_t)(0*512 + cb +  0))*512 + rg8;
  const float* wr1 = whh + ((size_t)(0*512 + cb + 16))*512 + rg8;
  const float* wr2 = whh + ((size_t)(1*512 + cb +  0))*512 + rg8;
  const float* wr3 = whh + ((size_t)(1*512 + cb + 16))*512 + rg8;
  const float* wr4 = whh + ((size_t)(2*512 + cb +  0))*512 + rg8;
  const float* wr5 = whh + ((size_t)(2*512 + cb + 16))*512 + rg8;

  DECLW(0) DECLW(1) DECLW(2) DECLW(3) DECLW(4) DECLW(5) DECLW(6) DECLW(7)
  DECLW(8) DECLW(9) DECLW(10) DECLW(11) DECLW(12) DECLW(13) DECLW(14) DECLW(15)
  LDK(0) LDK(1) LDK(2) LDK(3) LDK(4) LDK(5) LDK(6) LDK(7)
  LDK(8) LDK(9) LDK(10) LDK(11) LDK(12) LDK(13) LDK(14) LDK(15)

  float bR0 = bhh[cb],        bR1 = bhh[cb + 16];
  float bZ0 = bhh[512 + cb],  bZ1 = bhh[512 + cb + 16];
  float bN0 = bhh[1024 + cb], bN1 = bhh[1024 + cb + 16];

  f32x4 hreg0 = (f32x4){0,0,0,0}, hreg1 = (f32x4){0,0,0,0};

  for(int i = tid; i < 2*16*512; i += 1024) hl[i] = 0;
  __syncthreads();

  const uint16_t* xpd = xp + (size_t)dir*G3*MROWS;

  #pragma unroll 1
  for(int t = 0; t < 512; t++){
    int trow = dir ? (511 - t) : t;
    int rd = t & 1, wr = rd ^ 1;
    int rdoff = rd*8192 + rr*512;
    int wroff = wr*8192;
    int rowidx = trow*64 + bg*16 + rbase;

    // xp loads: 6 x 8B (4 consecutive batch rows each); latency hides under MFMA
    uint2 xq_r0 = *(const uint2*)&xpd[(size_t)(0*512 + cb     )*MROWS + rowidx];
    uint2 xq_r1 = *(const uint2*)&xpd[(size_t)(0*512 + cb + 16)*MROWS + rowidx];
    uint2 xq_z0 = *(const uint2*)&xpd[(size_t)(1*512 + cb     )*MROWS + rowidx];
    uint2 xq_z1 = *(const uint2*)&xpd[(size_t)(1*512 + cb + 16)*MROWS + rowidx];
    uint2 xq_n0 = *(const uint2*)&xpd[(size_t)(2*512 + cb     )*MROWS + rowidx];
    uint2 xq_n1 = *(const uint2*)&xpd[(size_t)(2*512 + cb + 16)*MROWS + rowidx];

    f32x4 acc0 = (f32x4){0,0,0,0}, acc1 = (f32x4){0,0,0,0}, acc2 = (f32x4){0,0,0,0};
    f32x4 acc3 = (f32x4){0,0,0,0}, acc4 = (f32x4){0,0,0,0}, acc5 = (f32x4){0,0,0,0};
    MK(0) MK(1) MK(2) MK(3) MK(4) MK(5) MK(6) MK(7)
    MK(8) MK(9) MK(10) MK(11) MK(12) MK(13) MK(14) MK(15)

    // gates: lane owns rows rbase..rbase+3, cols cb (s=0) and cb+16 (s=1)
    auto dogates = [&](const f32x4& aR, const f32x4& aZ, const f32x4& aN,
                       uint2 xr, uint2 xz, uint2 xn,
                       float bR_, float bZ_, float bN_, f32x4& hr, int scol){
      #pragma unroll
      for(int j=0;j<4;j++){
        uint32_t wrw = (j<2) ? xr.x : xr.y;
        uint32_t wzw = (j<2) ? xz.x : xz.y;
        uint32_t wnw = (j<2) ? xn.x : xn.y;
        int hi = j & 1;
        float rv = sig_f(bfsel(wrw,hi) + aR[j] + bR_);
        float zv = sig_f(bfsel(wzw,hi) + aZ[j] + bZ_);
        float nv = tanh_f(bfsel(wnw,hi) + rv*(aN[j] + bN_));
        float hnew = (1.f - zv)*nv + zv*hr[j];
        hr[j] = hnew;
        int row = rbase + j;
        hl[wroff + row*512 + (scol ^ ((row&7)<<4))] = f2bf_bits(hnew);
      }
    };
    dogates(acc0, acc2, acc4, xq_r0, xq_z0, xq_n0, bR0, bZ0, bN0, hreg0, cb);
    dogates(acc1, acc3, acc5, xq_r1, xq_z1, xq_n1, bR1, bZ1, bN1, hreg1, cb + 16);

    __syncthreads();   // h[wr] complete; prior reads of h[rd] done

    // coalesced f_out write: wave w writes row w (1 KB contiguous)
    {
      int row = w, c8 = (lane)*8;
      bf16x8 hv = *(const bf16x8*)&hl[wroff + row*512 + (c8 ^ ((row&7)<<4))];
      *(bf16x8*)&f_out[((size_t)trow*64 + bg*16 + row)*1024 + dir*512 + c8] = hv;
    }
  }
}

// ---------------------------------------------------------------- softmax over T per batch
__global__ void k_softmax(const float* __restrict__ scores_raw, float* __restrict__ wsm){
  __shared__ float sv[512];
  __shared__ float red[8];
  int b = blockIdx.x;
  int tid = threadIdx.x;
  float mymax = -1e30f;
  for(int t = tid; t < 512; t += 256){
    float s = tanhf(scores_raw[t*64 + b]);
    sv[t] = s;
    mymax = fmaxf(mymax, s);
  }
  #pragma unroll
  for(int off=1; off<64; off<<=1) mymax = fmaxf(mymax, __shfl_xor(mymax, off));
  if((tid&63)==0) red[tid>>6] = mymax;
  __syncthreads();
  float bmax = fmaxf(fmaxf(red[0],red[1]), fmaxf(red[2],red[3]));
  __syncthreads();
  float mysum = 0.f;
  for(int t = tid; t < 512; t += 256){
    float e = __expf(sv[t] - bmax);
    sv[t] = e;
    mysum += e;
  }
  #pragma unroll
  for(int off=1; off<64; off<<=1) mysum += __shfl_xor(mysum, off);
  if((tid&63)==0) red[tid>>6] = mysum;
  __syncthreads();
  float inv = 1.f/(red[0]+red[1]+red[2]+red[3]);
  for(int t = tid; t < 512; t += 256) wsm[b*512 + t] = sv[t]*inv;
}

// ---------------------------------------------------------------- ctx[b,d] = sum_t w[b,t] f[t,b,d]
__global__ void k_ctx(const uint16_t* __restrict__ f_out, const float* __restrict__ wsm, float* __restrict__ ctx){
  __shared__ float wloc[512];
  int b = blockIdx.x >> 2, chunk = blockIdx.x & 3;
  int tid = threadIdx.x;
  for(int t = tid; t < 512; t += 256) wloc[t] = wsm[b*512 + t];
  __syncthreads();
  int d = chunk*256 + tid;
  float acc = 0.f;
  #pragma unroll 8
  for(int t = 0; t < 512; t++)
    acc += wloc[t] * bf2f_bits(f_out[(size_t)(t*64 + b)*1024 + d]);
  ctx[b*1024 + d] = acc;
}

// ---------------------------------------------------------------- classifier
__global__ void k_cls1(const float* __restrict__ ctx, const float* __restrict__ w1,
                       const float* __restrict__ b1, float* __restrict__ hid){
  int idx = blockIdx.x*256 + threadIdx.x;   // 32768
  int b = idx >> 9, h = idx & 511;
  float acc = b1[h];
  for(int d = 0; d < 1024; d++) acc += ctx[b*1024 + d] * w1[d*512 + h];
  hid[idx] = fmaxf(acc, 0.f);
}

__global__ void k_cls2(const float* __restrict__ hid, const float* __restrict__ w2,
                       const float* __restrict__ b2, float* __restrict__ out){
  int idx = threadIdx.x;   // 640
  if(idx >= 640) return;
  int b = idx / 10, o = idx % 10;
  float acc = b2[o];
  for(int h = 0; h < 512; h++) acc += hid[b*512 + h] * w2[h*10 + o];
  out[idx] = acc;
}

// ---------------------------------------------------------------- launch
extern "C" void kernel_launch(void* const* d_in, const int* in_sizes, int n_in,
                              void* d_out, int out_size, void* d_ws, size_t ws_size,
                              hipStream_t stream)
{
  const float* emb    = (const float*)d_in[1];
  const float* w_ih_f = (const float*)d_in[2];
  const float* w_hh_f = (const float*)d_in[3];
  const float* b_ih_f = (const float*)d_in[4];
  const float* b_hh_f = (const float*)d_in[5];
  const float* w_ih_b = (const float*)d_in[6];
  const float* w_hh_b = (const float*)d_in[7];
  const float* b_ih_b = (const float*)d_in[8];
  const float* b_hh_b = (const float*)d_in[9];
  const float* attn_w = (const float*)d_in[10];
  const float* attn_b = (const float*)d_in[11];
  const float* ctx_w  = (const float*)d_in[12];
  const float* cls_w1 = (const float*)d_in[13];
  const float* cls_b1 = (const float*)d_in[14];
  const float* cls_w2 = (const float*)d_in[15];
  const float* cls_b2 = (const float*)d_in[16];
  float* out = (float*)d_out;

  char* ws = (char*)d_ws;
  size_t off = 0;
  auto alloc = [&](size_t bytes){ void* p = ws + off; off += (bytes + 255) & ~(size_t)255; return p; };
  uint16_t* femb = (uint16_t*)alloc((size_t)MROWS*DIN*2);      // emb bf16, later overlaid by f_out
  uint16_t* wcat = (uint16_t*)alloc((size_t)NC*DIN*2);
  uint16_t* xp   = (uint16_t*)alloc((size_t)MROWS*NC*2);       // transposed [3072][32768]
  uint16_t* awT  = (uint16_t*)alloc((size_t)1024*1024*2);
  float* scraw   = (float*)alloc((size_t)MROWS*4);
  float* wsm     = (float*)alloc((size_t)B_*T_*4);
  float* ctx     = (float*)alloc((size_t)B_*1024*4);
  float* hid     = (float*)alloc((size_t)B_*512*4);

  hipMemsetAsync(scraw, 0, (size_t)MROWS*4, stream);

  k_conv_emb<<<16384, 256, 0, stream>>>(emb, femb, (long)MROWS*DIN/8);
  k_conv_wcat<<<12288, 256, 0, stream>>>(w_ih_f, w_ih_b, wcat, NC*DIN);
  k_conv_awt<<<4096, 256, 0, stream>>>(attn_w, awT, 1024*1024);

  k_gemm_xp<<<dim3(24,256), 256, 0, stream>>>(femb, wcat, b_ih_f, b_ih_b, xp);

  k_recur<<<8, 1024, 0, stream>>>(xp, w_hh_f, w_hh_b, b_hh_f, b_hh_b, femb /* = f_out */);

  k_gemm_att<<<dim3(8,256), 256, 0, stream>>>(femb, awT, attn_b, ctx_w, scraw);
  k_softmax<<<64, 256, 0, stream>>>(scraw, wsm);
  k_ctx<<<256, 256, 0, stream>>>(femb, wsm, ctx);
  k_cls1<<<128, 256, 0, stream>>>(ctx, cls_w1, cls_b1, hid);
  k_cls2<<<1, 640, 0, stream>>>(hid, cls_w2, cls_b2, out);
}

// Round 5
// 22797.037 us; speedup vs baseline: 1.0438x; 1.0438x over previous
//
#include <hip/hip_runtime.h>
#include <stdint.h>

// Problem constants
#define T_   512
#define B_   64
#define DIN  1024
#define HID  512
#define G3   1536     // 3*HID
#define NC   3072     // both dirs of gates
#define MROWS 32768   // T_*B_

typedef __bf16 bf16;
typedef __bf16 bf16x8 __attribute__((ext_vector_type(8)));
typedef float  f32x4  __attribute__((ext_vector_type(4)));
typedef uint32_t u32x4 __attribute__((ext_vector_type(4)));

#define GLOBAL_AS __attribute__((address_space(1)))
#define LDS_AS    __attribute__((address_space(3)))

__device__ __forceinline__ uint16_t f2bf_bits(float x){
  union{float f; uint32_t u;} v; v.f = x;
  uint32_t u = v.u;
  u += 0x7FFFu + ((u >> 16) & 1u);   // round-to-nearest-even
  return (uint16_t)(u >> 16);
}
__device__ __forceinline__ float bf2f_bits(uint16_t h){
  union{uint32_t u; float f;} v; v.u = ((uint32_t)h) << 16;
  return v.f;
}
__device__ __forceinline__ float bfsel(uint32_t w, int hi){
  union{uint32_t u; float f;} v; v.u = hi ? (w & 0xffff0000u) : (w << 16);
  return v.f;
}
__device__ __forceinline__ float sig_f(float x){
  return 1.f/(1.f + __expf(-x));
}
__device__ __forceinline__ float tanh_f(float x){
  return 1.f - 2.f/(1.f + __expf(2.f*x));
}
__device__ __forceinline__ bf16x8 as_bf16x8(u32x4 u){
  union{u32x4 a; bf16x8 b;} c; c.a = u; return c.b;
}

// ---------------------------------------------------------------- converts
__global__ void k_conv_emb(const float* __restrict__ src, uint16_t* __restrict__ dst, long n8){
  long i = (long)blockIdx.x*blockDim.x + threadIdx.x;
  if(i >= n8) return;
  const float4* s = (const float4*)src;
  float4 a = s[i*2], b = s[i*2+1];
  uint32_t p0 = (uint32_t)f2bf_bits(a.x) | ((uint32_t)f2bf_bits(a.y) << 16);
  uint32_t p1 = (uint32_t)f2bf_bits(a.z) | ((uint32_t)f2bf_bits(a.w) << 16);
  uint32_t p2 = (uint32_t)f2bf_bits(b.x) | ((uint32_t)f2bf_bits(b.y) << 16);
  uint32_t p3 = (uint32_t)f2bf_bits(b.z) | ((uint32_t)f2bf_bits(b.w) << 16);
  ((uint4*)dst)[i] = make_uint4(p0,p1,p2,p3);
}

__global__ void k_conv_wcat(const float* __restrict__ wf, const float* __restrict__ wb, uint16_t* __restrict__ dst, int n){
  int i = blockIdx.x*256 + threadIdx.x;
  if(i >= n) return;
  float v = (i < G3*DIN) ? wf[i] : wb[i - G3*DIN];
  dst[i] = f2bf_bits(v);
}

__global__ void k_conv_awt(const float* __restrict__ aw, uint16_t* __restrict__ dst, int n){
  int i = blockIdx.x*256 + threadIdx.x;
  if(i >= n) return;
  int e = i >> 10, d = i & 1023;
  dst[i] = f2bf_bits(aw[d*1024 + e]);   // transpose: awT[e][d]
}

// ---------------------------------------------------------------- GEMM: xp = emb @ Wcat^T + bias
// OUTPUT TRANSPOSED: xp2[col][row], col in [0,3072), row in [0,32768)
__launch_bounds__(256)
__global__ void k_gemm_xp(const uint16_t* __restrict__ A, const uint16_t* __restrict__ Bw,
                          const float* __restrict__ bihf, const float* __restrict__ bihb,
                          uint16_t* __restrict__ C)
{
  __shared__ uint16_t lA[2][128*32];
  __shared__ uint16_t lB[2][128*32];
  const int K = 1024;
  int bn = blockIdx.x, bm = blockIdx.y;
  int tid = threadIdx.x;
  int lane = tid & 63, wid = tid >> 6;
  int wm = wid >> 1, wn = wid & 1;
  int rowBase = bm*128, colBase = bn*128;
  int rg = lane >> 4, rr = lane & 15;

  auto stage = [&](int buf, int kt){
    #pragma unroll
    for(int i=0;i<2;i++){
      int e = (i*256 + tid)*8;
      int r = e >> 5, c = e & 31;
      __builtin_amdgcn_global_load_lds((const GLOBAL_AS void*)(A + (size_t)(rowBase + r)*K + kt*32 + c),
                                       (LDS_AS void*)&lA[buf][e], 16, 0, 0);
    }
    #pragma unroll
    for(int i=0;i<2;i++){
      int e = (i*256 + tid)*8;
      int r = e >> 5, c = e & 31;
      __builtin_amdgcn_global_load_lds((const GLOBAL_AS void*)(Bw + (size_t)(colBase + r)*K + kt*32 + c),
                                       (LDS_AS void*)&lB[buf][e], 16, 0, 0);
    }
  };

  f32x4 acc[4][4];
  #pragma unroll
  for(int mi=0;mi<4;mi++)
    #pragma unroll
    for(int ni=0;ni<4;ni++) acc[mi][ni] = (f32x4){0.f,0.f,0.f,0.f};

  stage(0, 0);
  __syncthreads();
  for(int kt=0; kt<32; kt++){
    int buf = kt & 1;
    if(kt+1 < 32) stage(buf^1, kt+1);
    bf16x8 af[4], bfv[4];
    #pragma unroll
    for(int mi=0;mi<4;mi++)
      af[mi] = *(const bf16x8*)&lA[buf][(wm*64 + mi*16 + rr)*32 + rg*8];
    #pragma unroll
    for(int ni=0;ni<4;ni++)
      bfv[ni] = *(const bf16x8*)&lB[buf][(wn*64 + ni*16 + rr)*32 + rg*8];
    #pragma unroll
    for(int mi=0;mi<4;mi++)
      #pragma unroll
      for(int ni=0;ni<4;ni++)
        acc[mi][ni] = __builtin_amdgcn_mfma_f32_16x16x32_bf16(af[mi], bfv[ni], acc[mi][ni], 0,0,0);
    __syncthreads();
  }

  #pragma unroll
  for(int ni=0;ni<4;ni++){
    int col = colBase + wn*64 + ni*16 + rr;
    float bv = (col < G3) ? bihf[col] : bihb[col - G3];
    #pragma unroll
    for(int mi=0;mi<4;mi++){
      int row0 = rowBase + wm*64 + mi*16 + rg*4;
      uint32_t lo = (uint32_t)f2bf_bits(acc[mi][ni][0]+bv) | ((uint32_t)f2bf_bits(acc[mi][ni][1]+bv) << 16);
      uint32_t hi = (uint32_t)f2bf_bits(acc[mi][ni][2]+bv) | ((uint32_t)f2bf_bits(acc[mi][ni][3]+bv) << 16);
      *(uint2*)&C[(size_t)col*MROWS + row0] = make_uint2(lo, hi);
    }
  }
}

// ---------------------------------------------------------------- GEMM: attention, fused tanh + ctx_w dot
__launch_bounds__(256)
__global__ void k_gemm_att(const uint16_t* __restrict__ A, const uint16_t* __restrict__ Bw,
                           const float* __restrict__ attn_b, const float* __restrict__ ctx_w,
                           float* __restrict__ scores_raw)
{
  __shared__ uint16_t lA[2][128*32];
  __shared__ uint16_t lB[2][128*32];
  const int K = 1024;
  int bn = blockIdx.x, bm = blockIdx.y;
  int tid = threadIdx.x;
  int lane = tid & 63, wid = tid >> 6;
  int wm = wid >> 1, wn = wid & 1;
  int rowBase = bm*128, colBase = bn*128;
  int rg = lane >> 4, rr = lane & 15;

  auto stage = [&](int buf, int kt){
    #pragma unroll
    for(int i=0;i<2;i++){
      int e = (i*256 + tid)*8;
      int r = e >> 5, c = e & 31;
      __builtin_amdgcn_global_load_lds((const GLOBAL_AS void*)(A + (size_t)(rowBase + r)*K + kt*32 + c),
                                       (LDS_AS void*)&lA[buf][e], 16, 0, 0);
    }
    #pragma unroll
    for(int i=0;i<2;i++){
      int e = (i*256 + tid)*8;
      int r = e >> 5, c = e & 31;
      __builtin_amdgcn_global_load_lds((const GLOBAL_AS void*)(Bw + (size_t)(colBase + r)*K + kt*32 + c),
                                       (LDS_AS void*)&lB[buf][e], 16, 0, 0);
    }
  };

  f32x4 acc[4][4];
  #pragma unroll
  for(int mi=0;mi<4;mi++)
    #pragma unroll
    for(int ni=0;ni<4;ni++) acc[mi][ni] = (f32x4){0.f,0.f,0.f,0.f};

  stage(0, 0);
  __syncthreads();
  for(int kt=0; kt<32; kt++){
    int buf = kt & 1;
    if(kt+1 < 32) stage(buf^1, kt+1);
    bf16x8 af[4], bfv[4];
    #pragma unroll
    for(int mi=0;mi<4;mi++)
      af[mi] = *(const bf16x8*)&lA[buf][(wm*64 + mi*16 + rr)*32 + rg*8];
    #pragma unroll
    for(int ni=0;ni<4;ni++)
      bfv[ni] = *(const bf16x8*)&lB[buf][(wn*64 + ni*16 + rr)*32 + rg*8];
    #pragma unroll
    for(int mi=0;mi<4;mi++)
      #pragma unroll
      for(int ni=0;ni<4;ni++)
        acc[mi][ni] = __builtin_amdgcn_mfma_f32_16x16x32_bf16(af[mi], bfv[ni], acc[mi][ni], 0,0,0);
    __syncthreads();
  }

  float ab[4], cw[4];
  #pragma unroll
  for(int ni=0;ni<4;ni++){
    int col = colBase + wn*64 + ni*16 + rr;
    ab[ni] = attn_b[col];
    cw[ni] = ctx_w[col];
  }
  #pragma unroll
  for(int mi=0;mi<4;mi++){
    #pragma unroll
    for(int r=0;r<4;r++){
      float part = 0.f;
      #pragma unroll
      for(int ni=0;ni<4;ni++) part += tanhf(acc[mi][ni][r] + ab[ni]) * cw[ni];
      #pragma unroll
      for(int off=1; off<16; off<<=1) part += __shfl_xor(part, off);
      if(rr == 0){
        int row = rowBase + wm*64 + mi*16 + rg*4 + r;
        atomicAdd(&scores_raw[row], part);
      }
    }
  }
}

// ---------------------------------------------------------------- recurrence v5: W_hh pinned in AGPRs
// WG = (dir, 16 batch rows), 16 waves, 1 WG/CU. Wave w owns gh cols {g*512 + w*32 + s*16 + rr}.
// W fragments loaded from pre-converted bf16 and pinned via opaque asm into AGPR class
// (non-rematerializable). h in LDS double-buffer, XOR-swizzled. One barrier/step.
#define DECLW(k) u32x4 w0_##k, w1_##k, w2_##k, w3_##k, w4_##k, w5_##k;
#define LD1(tn,k) { w##tn##_##k = *(const u32x4*)(wr##tn + (size_t)(k)*32); \
                    asm volatile("" : "+a"(w##tn##_##k)); }
#define LDK(k) LD1(0,k) LD1(1,k) LD1(2,k) LD1(3,k) LD1(4,k) LD1(5,k)
#define MK(k) { bf16x8 a_ = *(const bf16x8*)&hl[rdoff + (((k)*32 + rg8) ^ rswz)]; \
  acc0 = __builtin_amdgcn_mfma_f32_16x16x32_bf16(a_, as_bf16x8(w0_##k), acc0, 0,0,0); \
  acc1 = __builtin_amdgcn_mfma_f32_16x16x32_bf16(a_, as_bf16x8(w1_##k), acc1, 0,0,0); \
  acc2 = __builtin_amdgcn_mfma_f32_16x16x32_bf16(a_, as_bf16x8(w2_##k), acc2, 0,0,0); \
  acc3 = __builtin_amdgcn_mfma_f32_16x16x32_bf16(a_, as_bf16x8(w3_##k), acc3, 0,0,0); \
  acc4 = __builtin_amdgcn_mfma_f32_16x16x32_bf16(a_, as_bf16x8(w4_##k), acc4, 0,0,0); \
  acc5 = __builtin_amdgcn_mfma_f32_16x16x32_bf16(a_, as_bf16x8(w5_##k), acc5, 0,0,0); }

__launch_bounds__(1024, 4)
__global__ void k_recur(const uint16_t* __restrict__ xp,     // transposed [3072][32768]
                        const uint16_t* __restrict__ whh_bf, // [2][1536][512] bf16
                        const float* __restrict__ bhhf, const float* __restrict__ bhhb,
                        uint16_t* __restrict__ f_out)
{
  __shared__ uint16_t hl[2*16*512];   // 32 KB, swizzled

  int bid = blockIdx.x;
  int dir = bid & 1;
  int bg  = bid >> 1;            // 0..3
  int tid = threadIdx.x;
  int lane = tid & 63, w = tid >> 6;      // 16 waves
  int rg = lane >> 4, rr = lane & 15;
  int rg8 = rg*8;
  int rswz = (rr & 7) << 4;
  int rbase = rg*4;              // C rows rbase..rbase+3
  int cb = w*32 + rr;            // h-col base (s adds 16)

  const uint16_t* wb = whh_bf + (size_t)dir*G3*HID;
  const float* bhh = dir ? bhhb : bhhf;

  // W fragment row pointers (tn = g*2+s), bf16 row-major [1536][512]
  const uint16_t* wr0 = wb + (size_t)(0*512 + cb +  0)*512 + rg8;
  const uint16_t* wr1 = wb + (size_t)(0*512 + cb + 16)*512 + rg8;
  const uint16_t* wr2 = wb + (size_t)(1*512 + cb +  0)*512 + rg8;
  const uint16_t* wr3 = wb + (size_t)(1*512 + cb + 16)*512 + rg8;
  const uint16_t* wr4 = wb + (size_t)(2*512 + cb +  0)*512 + rg8;
  const uint16_t* wr5 = wb + (size_t)(2*512 + cb + 16)*512 + rg8;

  DECLW(0) DECLW(1) DECLW(2) DECLW(3) DECLW(4) DECLW(5) DECLW(6) DECLW(7)
  DECLW(8) DECLW(9) DECLW(10) DECLW(11) DECLW(12) DECLW(13) DECLW(14) DECLW(15)
  LDK(0) LDK(1) LDK(2) LDK(3) LDK(4) LDK(5) LDK(6) LDK(7)
  LDK(8) LDK(9) LDK(10) LDK(11) LDK(12) LDK(13) LDK(14) LDK(15)

  float bR0 = bhh[cb],        bR1 = bhh[cb + 16];
  float bZ0 = bhh[512 + cb],  bZ1 = bhh[512 + cb + 16];
  float bN0 = bhh[1024 + cb], bN1 = bhh[1024 + cb + 16];

  f32x4 hreg0 = (f32x4){0,0,0,0}, hreg1 = (f32x4){0,0,0,0};

  for(int i = tid; i < 2*16*512; i += 1024) hl[i] = 0;
  __syncthreads();

  const uint16_t* xpd = xp + (size_t)dir*G3*MROWS;

  #pragma unroll 1
  for(int t = 0; t < 512; t++){
    int trow = dir ? (511 - t) : t;
    int rd = t & 1, wr = rd ^ 1;
    int rdoff = rd*8192 + rr*512;
    int wroff = wr*8192;
    int rowidx = trow*64 + bg*16 + rbase;

    // xp loads: 6 x 8B (4 consecutive batch rows each); latency hides under MFMA
    uint2 xq_r0 = *(const uint2*)&xpd[(size_t)(0*512 + cb     )*MROWS + rowidx];
    uint2 xq_r1 = *(const uint2*)&xpd[(size_t)(0*512 + cb + 16)*MROWS + rowidx];
    uint2 xq_z0 = *(const uint2*)&xpd[(size_t)(1*512 + cb     )*MROWS + rowidx];
    uint2 xq_z1 = *(const uint2*)&xpd[(size_t)(1*512 + cb + 16)*MROWS + rowidx];
    uint2 xq_n0 = *(const uint2*)&xpd[(size_t)(2*512 + cb     )*MROWS + rowidx];
    uint2 xq_n1 = *(const uint2*)&xpd[(size_t)(2*512 + cb + 16)*MROWS + rowidx];

    f32x4 acc0 = (f32x4){0,0,0,0}, acc1 = (f32x4){0,0,0,0}, acc2 = (f32x4){0,0,0,0};
    f32x4 acc3 = (f32x4){0,0,0,0}, acc4 = (f32x4){0,0,0,0}, acc5 = (f32x4){0,0,0,0};
    MK(0) MK(1) MK(2) MK(3) MK(4) MK(5) MK(6) MK(7)
    MK(8) MK(9) MK(10) MK(11) MK(12) MK(13) MK(14) MK(15)

    // gates: lane owns rows rbase..rbase+3, cols cb (s=0) and cb+16 (s=1)
    auto dogates = [&](const f32x4& aR, const f32x4& aZ, const f32x4& aN,
                       uint2 xr, uint2 xz, uint2 xn,
                       float bR_, float bZ_, float bN_, f32x4& hr, int scol){
      #pragma unroll
      for(int j=0;j<4;j++){
        uint32_t wrw = (j<2) ? xr.x : xr.y;
        uint32_t wzw = (j<2) ? xz.x : xz.y;
        uint32_t wnw = (j<2) ? xn.x : xn.y;
        int hi = j & 1;
        float rv = sig_f(bfsel(wrw,hi) + aR[j] + bR_);
        float zv = sig_f(bfsel(wzw,hi) + aZ[j] + bZ_);
        float nv = tanh_f(bfsel(wnw,hi) + rv*(aN[j] + bN_));
        float hnew = (1.f - zv)*nv + zv*hr[j];
        hr[j] = hnew;
        int row = rbase + j;
        hl[wroff + row*512 + (scol ^ ((row&7)<<4))] = f2bf_bits(hnew);
      }
    };
    dogates(acc0, acc2, acc4, xq_r0, xq_z0, xq_n0, bR0, bZ0, bN0, hreg0, cb);
    dogates(acc1, acc3, acc5, xq_r1, xq_z1, xq_n1, bR1, bZ1, bN1, hreg1, cb + 16);

    __syncthreads();   // h[wr] complete; prior reads of h[rd] done

    // coalesced f_out write: wave w writes row w (1 KB contiguous)
    {
      int row = w, c8 = (lane)*8;
      bf16x8 hv = *(const bf16x8*)&hl[wroff + row*512 + (c8 ^ ((row&7)<<4))];
      *(bf16x8*)&f_out[((size_t)trow*64 + bg*16 + row)*1024 + dir*512 + c8] = hv;
    }
  }
}

// ---------------------------------------------------------------- softmax over T per batch
__global__ void k_softmax(const float* __restrict__ scores_raw, float* __restrict__ wsm){
  __shared__ float sv[512];
  __shared__ float red[8];
  int b = blockIdx.x;
  int tid = threadIdx.x;
  float mymax = -1e30f;
  for(int t = tid; t < 512; t += 256){
    float s = tanhf(scores_raw[t*64 + b]);
    sv[t] = s;
    mymax = fmaxf(mymax, s);
  }
  #pragma unroll
  for(int off=1; off<64; off<<=1) mymax = fmaxf(mymax, __shfl_xor(mymax, off));
  if((tid&63)==0) red[tid>>6] = mymax;
  __syncthreads();
  float bmax = fmaxf(fmaxf(red[0],red[1]), fmaxf(red[2],red[3]));
  __syncthreads();
  float mysum = 0.f;
  for(int t = tid; t < 512; t += 256){
    float e = __expf(sv[t] - bmax);
    sv[t] = e;
    mysum += e;
  }
  #pragma unroll
  for(int off=1; off<64; off<<=1) mysum += __shfl_xor(mysum, off);
  if((tid&63)==0) red[tid>>6] = mysum;
  __syncthreads();
  float inv = 1.f/(red[0]+red[1]+red[2]+red[3]);
  for(int t = tid; t < 512; t += 256) wsm[b*512 + t] = sv[t]*inv;
}

// ---------------------------------------------------------------- ctx[b,d] = sum_t w[b,t] f[t,b,d]
__global__ void k_ctx(const uint16_t* __restrict__ f_out, const float* __restrict__ wsm, float* __restrict__ ctx){
  __shared__ float wloc[512];
  int b = blockIdx.x >> 2, chunk = blockIdx.x & 3;
  int tid = threadIdx.x;
  for(int t = tid; t < 512; t += 256) wloc[t] = wsm[b*512 + t];
  __syncthreads();
  int d = chunk*256 + tid;
  float acc = 0.f;
  #pragma unroll 8
  for(int t = 0; t < 512; t++)
    acc += wloc[t] * bf2f_bits(f_out[(size_t)(t*64 + b)*1024 + d]);
  ctx[b*1024 + d] = acc;
}

// ---------------------------------------------------------------- classifier
__global__ void k_cls1(const float* __restrict__ ctx, const float* __restrict__ w1,
                       const float* __restrict__ b1, float* __restrict__ hid){
  int idx = blockIdx.x*256 + threadIdx.x;   // 32768
  int b = idx >> 9, h = idx & 511;
  float acc = b1[h];
  for(int d = 0; d < 1024; d++) acc += ctx[b*1024 + d] * w1[d*512 + h];
  hid[idx] = fmaxf(acc, 0.f);
}

__global__ void k_cls2(const float* __restrict__ hid, const float* __restrict__ w2,
                       const float* __restrict__ b2, float* __restrict__ out){
  int idx = threadIdx.x;   // 640
  if(idx >= 640) return;
  int b = idx / 10, o = idx % 10;
  float acc = b2[o];
  for(int h = 0; h < 512; h++) acc += hid[b*512 + h] * w2[h*10 + o];
  out[idx] = acc;
}

// ---------------------------------------------------------------- launch
extern "C" void kernel_launch(void* const* d_in, const int* in_sizes, int n_in,
                              void* d_out, int out_size, void* d_ws, size_t ws_size,
                              hipStream_t stream)
{
  const float* emb    = (const float*)d_in[1];
  const float* w_ih_f = (const float*)d_in[2];
  const float* w_hh_f = (const float*)d_in[3];
  const float* b_ih_f = (const float*)d_in[4];
  const float* b_hh_f = (const float*)d_in[5];
  const float* w_ih_b = (const float*)d_in[6];
  const float* w_hh_b = (const float*)d_in[7];
  const float* b_ih_b = (const float*)d_in[8];
  const float* b_hh_b = (const float*)d_in[9];
  const float* attn_w = (const float*)d_in[10];
  const float* attn_b = (const float*)d_in[11];
  const float* ctx_w  = (const float*)d_in[12];
  const float* cls_w1 = (const float*)d_in[13];
  const float* cls_b1 = (const float*)d_in[14];
  const float* cls_w2 = (const float*)d_in[15];
  const float* cls_b2 = (const float*)d_in[16];
  float* out = (float*)d_out;

  char* ws = (char*)d_ws;
  size_t off = 0;
  auto alloc = [&](size_t bytes){ void* p = ws + off; off += (bytes + 255) & ~(size_t)255; return p; };
  uint16_t* femb = (uint16_t*)alloc((size_t)MROWS*DIN*2);      // emb bf16, later overlaid by f_out
  uint16_t* wcat = (uint16_t*)alloc((size_t)NC*DIN*2);
  uint16_t* xp   = (uint16_t*)alloc((size_t)MROWS*NC*2);       // transposed [3072][32768]
  uint16_t* awT  = (uint16_t*)alloc((size_t)1024*1024*2);
  uint16_t* whhb16 = (uint16_t*)alloc((size_t)2*G3*HID*2);     // [2][1536][512] bf16
  float* scraw   = (float*)alloc((size_t)MROWS*4);
  float* wsm     = (float*)alloc((size_t)B_*T_*4);
  float* ctx     = (float*)alloc((size_t)B_*1024*4);
  float* hid     = (float*)alloc((size_t)B_*512*4);

  hipMemsetAsync(scraw, 0, (size_t)MROWS*4, stream);

  k_conv_emb<<<16384, 256, 0, stream>>>(emb, femb, (long)MROWS*DIN/8);
  k_conv_wcat<<<12288, 256, 0, stream>>>(w_ih_f, w_ih_b, wcat, NC*DIN);
  k_conv_awt<<<4096, 256, 0, stream>>>(attn_w, awT, 1024*1024);
  k_conv_emb<<<384, 256, 0, stream>>>(w_hh_f, whhb16, (long)G3*HID/8);
  k_conv_emb<<<384, 256, 0, stream>>>(w_hh_b, whhb16 + (size_t)G3*HID, (long)G3*HID/8);

  k_gemm_xp<<<dim3(24,256), 256, 0, stream>>>(femb, wcat, b_ih_f, b_ih_b, xp);

  k_recur<<<8, 1024, 0, stream>>>(xp, whhb16, b_hh_f, b_hh_b, femb /* = f_out */);

  k_gemm_att<<<dim3(8,256), 256, 0, stream>>>(femb, awT, attn_b, ctx_w, scraw);
  k_softmax<<<64, 256, 0, stream>>>(scraw, wsm);
  k_ctx<<<256, 256, 0, stream>>>(femb, wsm, ctx);
  k_cls1<<<128, 256, 0, stream>>>(ctx, cls_w1, cls_b1, hid);
  k_cls2<<<1, 640, 0, stream>>>(hid, cls_w2, cls_b2, out);
}

// Round 6
// 2071.534 us; speedup vs baseline: 11.4867x; 11.0049x over previous
//
#include <hip/hip_runtime.h>
#include <stdint.h>

// Problem constants
#define T_   512
#define B_   64
#define DIN  1024
#define HID  512
#define G3   1536     // 3*HID
#define NC   3072     // both dirs of gates
#define MROWS 32768   // T_*B_

typedef __bf16 bf16;
typedef __bf16 bf16x8 __attribute__((ext_vector_type(8)));
typedef float  f32x4  __attribute__((ext_vector_type(4)));

#define GLOBAL_AS __attribute__((address_space(1)))
#define LDS_AS    __attribute__((address_space(3)))

__device__ __forceinline__ uint16_t f2bf_bits(float x){
  union{float f; uint32_t u;} v; v.f = x;
  uint32_t u = v.u;
  u += 0x7FFFu + ((u >> 16) & 1u);   // round-to-nearest-even
  return (uint16_t)(u >> 16);
}
__device__ __forceinline__ float bf2f_bits(uint16_t h){
  union{uint32_t u; float f;} v; v.u = ((uint32_t)h) << 16;
  return v.f;
}
__device__ __forceinline__ float sig_f(float x){
  return 1.f/(1.f + __expf(-x));
}
__device__ __forceinline__ float tanh_f(float x){
  return 1.f - 2.f/(1.f + __expf(2.f*x));
}

// ---------------------------------------------------------------- converts
__global__ void k_conv_emb(const float* __restrict__ src, uint16_t* __restrict__ dst, long n8){
  long i = (long)blockIdx.x*blockDim.x + threadIdx.x;
  if(i >= n8) return;
  const float4* s = (const float4*)src;
  float4 a = s[i*2], b = s[i*2+1];
  uint32_t p0 = (uint32_t)f2bf_bits(a.x) | ((uint32_t)f2bf_bits(a.y) << 16);
  uint32_t p1 = (uint32_t)f2bf_bits(a.z) | ((uint32_t)f2bf_bits(a.w) << 16);
  uint32_t p2 = (uint32_t)f2bf_bits(b.x) | ((uint32_t)f2bf_bits(b.y) << 16);
  uint32_t p3 = (uint32_t)f2bf_bits(b.z) | ((uint32_t)f2bf_bits(b.w) << 16);
  ((uint4*)dst)[i] = make_uint4(p0,p1,p2,p3);
}

__global__ void k_conv_wcat(const float* __restrict__ wf, const float* __restrict__ wb, uint16_t* __restrict__ dst, int n){
  int i = blockIdx.x*256 + threadIdx.x;
  if(i >= n) return;
  float v = (i < G3*DIN) ? wf[i] : wb[i - G3*DIN];
  dst[i] = f2bf_bits(v);
}

__global__ void k_conv_awt(const float* __restrict__ aw, uint16_t* __restrict__ dst, int n){
  int i = blockIdx.x*256 + threadIdx.x;
  if(i >= n) return;
  int e = i >> 10, d = i & 1023;
  dst[i] = f2bf_bits(aw[d*1024 + e]);   // transpose: awT[e][d]
}

// W_hh -> bf16, member-sliced, chunk-XOR-pre-swizzled so k_recur's
// global_load_lds is linear and ds_reads are bank-conflict-free.
// wmem[(dir*16+member)*96 + lc][chunk c] (16B units), source chunk = c ^ (lc&7),
// gcol = (ct>>1)*512 + member*32 + (ct&1)*16 + (lc&15), ct = lc>>4.
__global__ void k_conv_whh(const float* __restrict__ wf, const float* __restrict__ wb, uint4* __restrict__ wmem){
  int idx = blockIdx.x*256 + threadIdx.x;   // 196608 total
  if(idx >= 2*16*96*64) return;
  int c  = idx & 63;
  int t2 = idx >> 6;
  int lc = t2 % 96;
  int t3 = t2 / 96;
  int member = t3 & 15, dir = t3 >> 4;
  int ct = lc >> 4, rr = lc & 15;
  int gcol = (ct >> 1)*512 + member*32 + (ct & 1)*16 + rr;
  int csrc = c ^ (lc & 7);
  const float* src = (dir ? wb : wf) + (size_t)gcol*512 + csrc*8;
  float4 f0 = *(const float4*)src;
  float4 f1 = *(const float4*)(src + 4);
  uint32_t p0 = (uint32_t)f2bf_bits(f0.x) | ((uint32_t)f2bf_bits(f0.y) << 16);
  uint32_t p1 = (uint32_t)f2bf_bits(f0.z) | ((uint32_t)f2bf_bits(f0.w) << 16);
  uint32_t p2 = (uint32_t)f2bf_bits(f1.x) | ((uint32_t)f2bf_bits(f1.y) << 16);
  uint32_t p3 = (uint32_t)f2bf_bits(f1.z) | ((uint32_t)f2bf_bits(f1.w) << 16);
  wmem[idx] = make_uint4(p0,p1,p2,p3);
}

// ---------------------------------------------------------------- GEMM: xp = emb @ Wcat^T + bias
// OUTPUT TRANSPOSED: xp2[col][row], col in [0,3072), row in [0,32768)
__launch_bounds__(256)
__global__ void k_gemm_xp(const uint16_t* __restrict__ A, const uint16_t* __restrict__ Bw,
                          const float* __restrict__ bihf, const float* __restrict__ bihb,
                          uint16_t* __restrict__ C)
{
  __shared__ uint16_t lA[2][128*32];
  __shared__ uint16_t lB[2][128*32];
  const int K = 1024;
  int bn = blockIdx.x, bm = blockIdx.y;
  int tid = threadIdx.x;
  int lane = tid & 63, wid = tid >> 6;
  int wm = wid >> 1, wn = wid & 1;
  int rowBase = bm*128, colBase = bn*128;
  int rg = lane >> 4, rr = lane & 15;

  auto stage = [&](int buf, int kt){
    #pragma unroll
    for(int i=0;i<2;i++){
      int e = (i*256 + tid)*8;
      int r = e >> 5, c = e & 31;
      __builtin_amdgcn_global_load_lds((const GLOBAL_AS void*)(A + (size_t)(rowBase + r)*K + kt*32 + c),
                                       (LDS_AS void*)&lA[buf][e], 16, 0, 0);
    }
    #pragma unroll
    for(int i=0;i<2;i++){
      int e = (i*256 + tid)*8;
      int r = e >> 5, c = e & 31;
      __builtin_amdgcn_global_load_lds((const GLOBAL_AS void*)(Bw + (size_t)(colBase + r)*K + kt*32 + c),
                                       (LDS_AS void*)&lB[buf][e], 16, 0, 0);
    }
  };

  f32x4 acc[4][4];
  #pragma unroll
  for(int mi=0;mi<4;mi++)
    #pragma unroll
    for(int ni=0;ni<4;ni++) acc[mi][ni] = (f32x4){0.f,0.f,0.f,0.f};

  stage(0, 0);
  __syncthreads();
  for(int kt=0; kt<32; kt++){
    int buf = kt & 1;
    if(kt+1 < 32) stage(buf^1, kt+1);
    bf16x8 af[4], bfv[4];
    #pragma unroll
    for(int mi=0;mi<4;mi++)
      af[mi] = *(const bf16x8*)&lA[buf][(wm*64 + mi*16 + rr)*32 + rg*8];
    #pragma unroll
    for(int ni=0;ni<4;ni++)
      bfv[ni] = *(const bf16x8*)&lB[buf][(wn*64 + ni*16 + rr)*32 + rg*8];
    #pragma unroll
    for(int mi=0;mi<4;mi++)
      #pragma unroll
      for(int ni=0;ni<4;ni++)
        acc[mi][ni] = __builtin_amdgcn_mfma_f32_16x16x32_bf16(af[mi], bfv[ni], acc[mi][ni], 0,0,0);
    __syncthreads();
  }

  #pragma unroll
  for(int ni=0;ni<4;ni++){
    int col = colBase + wn*64 + ni*16 + rr;
    float bv = (col < G3) ? bihf[col] : bihb[col - G3];
    #pragma unroll
    for(int mi=0;mi<4;mi++){
      int row0 = rowBase + wm*64 + mi*16 + rg*4;
      uint32_t lo = (uint32_t)f2bf_bits(acc[mi][ni][0]+bv) | ((uint32_t)f2bf_bits(acc[mi][ni][1]+bv) << 16);
      uint32_t hi = (uint32_t)f2bf_bits(acc[mi][ni][2]+bv) | ((uint32_t)f2bf_bits(acc[mi][ni][3]+bv) << 16);
      *(uint2*)&C[(size_t)col*MROWS + row0] = make_uint2(lo, hi);
    }
  }
}

// ---------------------------------------------------------------- GEMM: attention, fused tanh + ctx_w dot
__launch_bounds__(256)
__global__ void k_gemm_att(const uint16_t* __restrict__ A, const uint16_t* __restrict__ Bw,
                           const float* __restrict__ attn_b, const float* __restrict__ ctx_w,
                           float* __restrict__ scores_raw)
{
  __shared__ uint16_t lA[2][128*32];
  __shared__ uint16_t lB[2][128*32];
  const int K = 1024;
  int bn = blockIdx.x, bm = blockIdx.y;
  int tid = threadIdx.x;
  int lane = tid & 63, wid = tid >> 6;
  int wm = wid >> 1, wn = wid & 1;
  int rowBase = bm*128, colBase = bn*128;
  int rg = lane >> 4, rr = lane & 15;

  auto stage = [&](int buf, int kt){
    #pragma unroll
    for(int i=0;i<2;i++){
      int e = (i*256 + tid)*8;
      int r = e >> 5, c = e & 31;
      __builtin_amdgcn_global_load_lds((const GLOBAL_AS void*)(A + (size_t)(rowBase + r)*K + kt*32 + c),
                                       (LDS_AS void*)&lA[buf][e], 16, 0, 0);
    }
    #pragma unroll
    for(int i=0;i<2;i++){
      int e = (i*256 + tid)*8;
      int r = e >> 5, c = e & 31;
      __builtin_amdgcn_global_load_lds((const GLOBAL_AS void*)(Bw + (size_t)(colBase + r)*K + kt*32 + c),
                                       (LDS_AS void*)&lB[buf][e], 16, 0, 0);
    }
  };

  f32x4 acc[4][4];
  #pragma unroll
  for(int mi=0;mi<4;mi++)
    #pragma unroll
    for(int ni=0;ni<4;ni++) acc[mi][ni] = (f32x4){0.f,0.f,0.f,0.f};

  stage(0, 0);
  __syncthreads();
  for(int kt=0; kt<32; kt++){
    int buf = kt & 1;
    if(kt+1 < 32) stage(buf^1, kt+1);
    bf16x8 af[4], bfv[4];
    #pragma unroll
    for(int mi=0;mi<4;mi++)
      af[mi] = *(const bf16x8*)&lA[buf][(wm*64 + mi*16 + rr)*32 + rg*8];
    #pragma unroll
    for(int ni=0;ni<4;ni++)
      bfv[ni] = *(const bf16x8*)&lB[buf][(wn*64 + ni*16 + rr)*32 + rg*8];
    #pragma unroll
    for(int mi=0;mi<4;mi++)
      #pragma unroll
      for(int ni=0;ni<4;ni++)
        acc[mi][ni] = __builtin_amdgcn_mfma_f32_16x16x32_bf16(af[mi], bfv[ni], acc[mi][ni], 0,0,0);
    __syncthreads();
  }

  float ab[4], cw[4];
  #pragma unroll
  for(int ni=0;ni<4;ni++){
    int col = colBase + wn*64 + ni*16 + rr;
    ab[ni] = attn_b[col];
    cw[ni] = ctx_w[col];
  }
  #pragma unroll
  for(int mi=0;mi<4;mi++){
    #pragma unroll
    for(int r=0;r<4;r++){
      float part = 0.f;
      #pragma unroll
      for(int ni=0;ni<4;ni++) part += tanhf(acc[mi][ni][r] + ab[ni]) * cw[ni];
      #pragma unroll
      for(int off=1; off<16; off<<=1) part += __shfl_xor(part, off);
      if(rr == 0){
        int row = rowBase + wm*64 + mi*16 + rg*4 + r;
        atomicAdd(&scores_raw[row], part);
      }
    }
  }
}

// ---------------------------------------------------------------- recurrence v6: 8 chains x 16 members, W in LDS,
// flag-based LLC sync (r2-proven protocol), batched independent h loads, LDS-staged h.
// WG = (dir, bg 16-rows, member 32-cols). 768 threads = 12 waves: wave w -> (ct=w>>1, kh=w&1).
__launch_bounds__(768, 3)
__global__ void k_recur(const uint16_t* __restrict__ xp,     // transposed [3072][32768]
                        const uint4* __restrict__ wmem,      // pre-swizzled W slices
                        const float* __restrict__ bhhf, const float* __restrict__ bhhb,
                        uint16_t* __restrict__ hpub,         // [2][2][64][512] bf16
                        unsigned* __restrict__ flags,        // [8][16]
                        uint16_t* __restrict__ f_out)
{
  __shared__ uint16_t Wl[96*512];        // 96 KB
  __shared__ uint16_t hl[16*512];        // 16 KB, chunk-XOR swizzled
  __shared__ float    ghl[2*6*16*17];    // 12.75 KB

  int bid = blockIdx.x;
  int dir = bid & 1, bg = (bid >> 1) & 3, member = bid >> 3;
  int chain = bid & 7;
  int jb = member*32;
  int tid = threadIdx.x;
  int lane = tid & 63, w = tid >> 6;
  int rr = lane & 15, rg = lane >> 4;
  int ct = w >> 1, kh = w & 1;

  // stage W slice: linear global_load_lds (layout pre-swizzled by k_conv_whh)
  const uint4* wsrc = wmem + (size_t)(dir*16 + member)*6144;
  for(int e = tid; e < 6144; e += 768)
    __builtin_amdgcn_global_load_lds((const GLOBAL_AS void*)(wsrc + e),
                                     (LDS_AS void*)&Wl[e*8], 16, 0, 0);
  for(int i = tid; i < 2*6*16*17; i += 768) ghl[i] = 0.f;

  // gate-thread constants: thread (tid<512) owns (row=tid>>5, col=tid&31)
  int grow = tid >> 5, gcol = tid & 31;
  const float* bhh = dir ? bhhb : bhhf;
  float bR = 0.f, bZ = 0.f, bN = 0.f, hprev = 0.f;
  if(tid < 512){
    bR = bhh[jb + gcol];
    bZ = bhh[512 + jb + gcol];
    bN = bhh[1024 + jb + gcol];
  }
  __syncthreads();   // W staged (barrier drains vmcnt), ghl zeroed

  #pragma unroll 1
  for(int t = 0; t < 512; t++){
    int trow = dir ? (511 - t) : t;

    // xp loads early (immutable data; vmcnt waited at gate use)
    uint16_t xr16 = 0, xz16 = 0, xn16 = 0;
    if(tid < 512){
      size_t ro  = (size_t)(trow*64 + bg*16 + grow);
      size_t cb0 = (size_t)(dir*G3 + jb + gcol);
      xr16 = xp[(cb0 +    0)*MROWS + ro];
      xz16 = xp[(cb0 +  512)*MROWS + ro];
      xn16 = xp[(cb0 + 1024)*MROWS + ro];
    }

    if(t > 0){
      // poll: wave 0, lanes 0..15 watch the 16 member flags of this chain
      if(w == 0){
        const unsigned* fl = flags + chain*16;
        bool idle = (lane >= 16);
        while(true){
          bool ok = idle ||
            (__hip_atomic_load(&fl[lane & 15], __ATOMIC_RELAXED, __HIP_MEMORY_SCOPE_AGENT) >= (unsigned)t);
          if(__all(ok)) break;
          __builtin_amdgcn_s_sleep(1);
        }
      }
      __syncthreads();   // flags ok -> h_t complete at LLC

      // staging: waves 0-1 pull 16 KB h (own bg rows) via 16 independent agent loads/lane
      if(w < 2){
        const unsigned long long* hs =
          (const unsigned long long*)(hpub + (size_t)((dir*2 + (t & 1))*64 + bg*16)*512);
        int L = tid;   // 0..127
        unsigned long long hv[16];
        #pragma unroll
        for(int it = 0; it < 16; it++)
          hv[it] = __hip_atomic_load(hs + it*128 + L, __ATOMIC_RELAXED, __HIP_MEMORY_SCOPE_AGENT);
        #pragma unroll
        for(int it = 0; it < 16; it++){
          int row = it;                    // idx = it*128+L -> idx>>7 == it
          int col4 = L*4;
          int pos = row*512 + (((col4 >> 3) ^ (row & 7))*8) + (col4 & 7);
          *(unsigned long long*)&hl[pos] = hv[it];
        }
      }
      __syncthreads();   // hl ready

      // gh partial: wave (ct, kh): 16 rows x 16 cols over K-half kh
      f32x4 acc = (f32x4){0.f,0.f,0.f,0.f};
      #pragma unroll
      for(int ks = 0; ks < 8; ks++){
        int ch = kh*32 + ks*4 + rg;
        int sw = (ch ^ (rr & 7))*8;
        bf16x8 a = *(const bf16x8*)&hl[rr*512 + sw];
        bf16x8 b = *(const bf16x8*)&Wl[(ct*16 + rr)*512 + sw];
        acc = __builtin_amdgcn_mfma_f32_16x16x32_bf16(a, b, acc, 0,0,0);
      }
      #pragma unroll
      for(int j = 0; j < 4; j++)
        ghl[((kh*6 + ct)*16 + rg*4 + j)*17 + rr] = acc[j];
    }
    __syncthreads();   // ghl ready (zeros at t==0)

    // gates
    if(tid < 512){
      int c16 = gcol >> 4, cc = gcol & 15;
      float gR = ghl[((0 + c16)*16 + grow)*17 + cc] + ghl[((6  + c16)*16 + grow)*17 + cc] + bR;
      float gZ = ghl[((2 + c16)*16 + grow)*17 + cc] + ghl[((8  + c16)*16 + grow)*17 + cc] + bZ;
      float gN = ghl[((4 + c16)*16 + grow)*17 + cc] + ghl[((10 + c16)*16 + grow)*17 + cc] + bN;
      float rv = sig_f(bf2f_bits(xr16) + gR);
      float zv = sig_f(bf2f_bits(xz16) + gZ);
      float nv = tanh_f(bf2f_bits(xn16) + rv*gN);
      float hnew = (1.f - zv)*nv + zv*hprev;
      hprev = hnew;
      unsigned hb = (unsigned)f2bf_bits(hnew);
      unsigned nb = (unsigned)__shfl_down((int)hb, 1);
      if((tid & 1) == 0){
        unsigned pk = hb | (nb << 16);
        __hip_atomic_store(
          (unsigned*)(hpub + (size_t)((dir*2 + ((t+1) & 1))*64 + bg*16 + grow)*512 + jb + gcol),
          pk, __ATOMIC_RELAXED, __HIP_MEMORY_SCOPE_AGENT);
        *(unsigned*)&f_out[((size_t)trow*64 + bg*16 + grow)*1024 + dir*512 + jb + gcol] = pk;
      }
    }
    __syncthreads();   // barrier drains vmcnt(0): all publishes acked at LLC
    if(tid == 0)
      __hip_atomic_store(&flags[chain*16 + member], (unsigned)(t+1),
                         __ATOMIC_RELAXED, __HIP_MEMORY_SCOPE_AGENT);
  }
}

// ---------------------------------------------------------------- softmax over T per batch
__global__ void k_softmax(const float* __restrict__ scores_raw, float* __restrict__ wsm){
  __shared__ float sv[512];
  __shared__ float red[8];
  int b = blockIdx.x;
  int tid = threadIdx.x;
  float mymax = -1e30f;
  for(int t = tid; t < 512; t += 256){
    float s = tanhf(scores_raw[t*64 + b]);
    sv[t] = s;
    mymax = fmaxf(mymax, s);
  }
  #pragma unroll
  for(int off=1; off<64; off<<=1) mymax = fmaxf(mymax, __shfl_xor(mymax, off));
  if((tid&63)==0) red[tid>>6] = mymax;
  __syncthreads();
  float bmax = fmaxf(fmaxf(red[0],red[1]), fmaxf(red[2],red[3]));
  __syncthreads();
  float mysum = 0.f;
  for(int t = tid; t < 512; t += 256){
    float e = __expf(sv[t] - bmax);
    sv[t] = e;
    mysum += e;
  }
  #pragma unroll
  for(int off=1; off<64; off<<=1) mysum += __shfl_xor(mysum, off);
  if((tid&63)==0) red[tid>>6] = mysum;
  __syncthreads();
  float inv = 1.f/(red[0]+red[1]+red[2]+red[3]);
  for(int t = tid; t < 512; t += 256) wsm[b*512 + t] = sv[t]*inv;
}

// ---------------------------------------------------------------- ctx[b,d] = sum_t w[b,t] f[t,b,d]
__global__ void k_ctx(const uint16_t* __restrict__ f_out, const float* __restrict__ wsm, float* __restrict__ ctx){
  __shared__ float wloc[512];
  int b = blockIdx.x >> 2, chunk = blockIdx.x & 3;
  int tid = threadIdx.x;
  for(int t = tid; t < 512; t += 256) wloc[t] = wsm[b*512 + t];
  __syncthreads();
  int d = chunk*256 + tid;
  float acc = 0.f;
  #pragma unroll 8
  for(int t = 0; t < 512; t++)
    acc += wloc[t] * bf2f_bits(f_out[(size_t)(t*64 + b)*1024 + d]);
  ctx[b*1024 + d] = acc;
}

// ---------------------------------------------------------------- classifier
__global__ void k_cls1(const float* __restrict__ ctx, const float* __restrict__ w1,
                       const float* __restrict__ b1, float* __restrict__ hid){
  int idx = blockIdx.x*256 + threadIdx.x;   // 32768
  int b = idx >> 9, h = idx & 511;
  float acc = b1[h];
  for(int d = 0; d < 1024; d++) acc += ctx[b*1024 + d] * w1[d*512 + h];
  hid[idx] = fmaxf(acc, 0.f);
}

__global__ void k_cls2(const float* __restrict__ hid, const float* __restrict__ w2,
                       const float* __restrict__ b2, float* __restrict__ out){
  int idx = threadIdx.x;   // 640
  if(idx >= 640) return;
  int b = idx / 10, o = idx % 10;
  float acc = b2[o];
  for(int h = 0; h < 512; h++) acc += hid[b*512 + h] * w2[h*10 + o];
  out[idx] = acc;
}

// ---------------------------------------------------------------- launch
extern "C" void kernel_launch(void* const* d_in, const int* in_sizes, int n_in,
                              void* d_out, int out_size, void* d_ws, size_t ws_size,
                              hipStream_t stream)
{
  const float* emb    = (const float*)d_in[1];
  const float* w_ih_f = (const float*)d_in[2];
  const float* w_hh_f = (const float*)d_in[3];
  const float* b_ih_f = (const float*)d_in[4];
  const float* b_hh_f = (const float*)d_in[5];
  const float* w_ih_b = (const float*)d_in[6];
  const float* w_hh_b = (const float*)d_in[7];
  const float* b_ih_b = (const float*)d_in[8];
  const float* b_hh_b = (const float*)d_in[9];
  const float* attn_w = (const float*)d_in[10];
  const float* attn_b = (const float*)d_in[11];
  const float* ctx_w  = (const float*)d_in[12];
  const float* cls_w1 = (const float*)d_in[13];
  const float* cls_b1 = (const float*)d_in[14];
  const float* cls_w2 = (const float*)d_in[15];
  const float* cls_b2 = (const float*)d_in[16];
  float* out = (float*)d_out;

  char* ws = (char*)d_ws;
  size_t off = 0;
  auto alloc = [&](size_t bytes){ void* p = ws + off; off += (bytes + 255) & ~(size_t)255; return p; };
  uint16_t* femb = (uint16_t*)alloc((size_t)MROWS*DIN*2);      // emb bf16, later overlaid by f_out
  uint16_t* wcat = (uint16_t*)alloc((size_t)NC*DIN*2);
  uint16_t* xp   = (uint16_t*)alloc((size_t)MROWS*NC*2);       // transposed [3072][32768]
  uint16_t* awT  = (uint16_t*)alloc((size_t)1024*1024*2);
  uint4*    wmem = (uint4*)alloc((size_t)2*16*96*64*16);       // 3 MB pre-swizzled W
  uint16_t* hpub = (uint16_t*)alloc((size_t)2*2*64*512*2);     // 256 KB
  unsigned* flags= (unsigned*)alloc(4096);
  float* scraw   = (float*)alloc((size_t)MROWS*4);
  float* wsm     = (float*)alloc((size_t)B_*T_*4);
  float* ctx     = (float*)alloc((size_t)B_*1024*4);
  float* hid     = (float*)alloc((size_t)B_*512*4);

  hipMemsetAsync(flags, 0, 4096, stream);
  hipMemsetAsync(scraw, 0, (size_t)MROWS*4, stream);

  k_conv_emb<<<16384, 256, 0, stream>>>(emb, femb, (long)MROWS*DIN/8);
  k_conv_wcat<<<12288, 256, 0, stream>>>(w_ih_f, w_ih_b, wcat, NC*DIN);
  k_conv_awt<<<4096, 256, 0, stream>>>(attn_w, awT, 1024*1024);
  k_conv_whh<<<768, 256, 0, stream>>>(w_hh_f, w_hh_b, wmem);

  k_gemm_xp<<<dim3(24,256), 256, 0, stream>>>(femb, wcat, b_ih_f, b_ih_b, xp);

  k_recur<<<128, 768, 0, stream>>>(xp, wmem, b_hh_f, b_hh_b, hpub, flags, femb /* = f_out */);

  k_gemm_att<<<dim3(8,256), 256, 0, stream>>>(femb, awT, attn_b, ctx_w, scraw);
  k_softmax<<<64, 256, 0, stream>>>(scraw, wsm);
  k_ctx<<<256, 256, 0, stream>>>(femb, wsm, ctx);
  k_cls1<<<128, 256, 0, stream>>>(ctx, cls_w1, cls_b1, hid);
  k_cls2<<<1, 640, 0, stream>>>(hid, cls_w2, cls_b2, out);
}

// Round 7
// 1949.172 us; speedup vs baseline: 12.2077x; 1.0628x over previous
//
#include <hip/hip_runtime.h>
#include <stdint.h>

// Problem constants
#define T_   512
#define B_   64
#define DIN  1024
#define HID  512
#define G3   1536     // 3*HID
#define NC   3072     // both dirs of gates
#define MROWS 32768   // T_*B_

typedef __bf16 bf16;
typedef __bf16 bf16x8 __attribute__((ext_vector_type(8)));
typedef float  f32x4  __attribute__((ext_vector_type(4)));

#define GLOBAL_AS __attribute__((address_space(1)))
#define LDS_AS    __attribute__((address_space(3)))

__device__ __forceinline__ uint16_t f2bf_bits(float x){
  union{float f; uint32_t u;} v; v.f = x;
  uint32_t u = v.u;
  u += 0x7FFFu + ((u >> 16) & 1u);   // round-to-nearest-even
  return (uint16_t)(u >> 16);
}
__device__ __forceinline__ float bf2f_bits(uint16_t h){
  union{uint32_t u; float f;} v; v.u = ((uint32_t)h) << 16;
  return v.f;
}
__device__ __forceinline__ float sig_f(float x){
  return 1.f/(1.f + __expf(-x));
}
__device__ __forceinline__ float tanh_f(float x){
  return 1.f - 2.f/(1.f + __expf(2.f*x));
}

// ---------------------------------------------------------------- converts
__global__ void k_conv_emb(const float* __restrict__ src, uint16_t* __restrict__ dst, long n8){
  long i = (long)blockIdx.x*blockDim.x + threadIdx.x;
  if(i >= n8) return;
  const float4* s = (const float4*)src;
  float4 a = s[i*2], b = s[i*2+1];
  uint32_t p0 = (uint32_t)f2bf_bits(a.x) | ((uint32_t)f2bf_bits(a.y) << 16);
  uint32_t p1 = (uint32_t)f2bf_bits(a.z) | ((uint32_t)f2bf_bits(a.w) << 16);
  uint32_t p2 = (uint32_t)f2bf_bits(b.x) | ((uint32_t)f2bf_bits(b.y) << 16);
  uint32_t p3 = (uint32_t)f2bf_bits(b.z) | ((uint32_t)f2bf_bits(b.w) << 16);
  ((uint4*)dst)[i] = make_uint4(p0,p1,p2,p3);
}

__global__ void k_conv_wcat(const float* __restrict__ wf, const float* __restrict__ wb, uint16_t* __restrict__ dst, int n){
  int i = blockIdx.x*256 + threadIdx.x;
  if(i >= n) return;
  float v = (i < G3*DIN) ? wf[i] : wb[i - G3*DIN];
  dst[i] = f2bf_bits(v);
}

__global__ void k_conv_awt(const float* __restrict__ aw, uint16_t* __restrict__ dst, int n){
  int i = blockIdx.x*256 + threadIdx.x;
  if(i >= n) return;
  int e = i >> 10, d = i & 1023;
  dst[i] = f2bf_bits(aw[d*1024 + e]);   // transpose: awT[e][d]
}

// W_hh -> bf16, member-sliced, chunk-XOR-pre-swizzled so k_recur's
// global_load_lds is linear and ds_reads are bank-conflict-free.
__global__ void k_conv_whh(const float* __restrict__ wf, const float* __restrict__ wb, uint4* __restrict__ wmem){
  int idx = blockIdx.x*256 + threadIdx.x;   // 196608 total
  if(idx >= 2*16*96*64) return;
  int c  = idx & 63;
  int t2 = idx >> 6;
  int lc = t2 % 96;
  int t3 = t2 / 96;
  int member = t3 & 15, dir = t3 >> 4;
  int ct = lc >> 4, rr = lc & 15;
  int gcol = (ct >> 1)*512 + member*32 + (ct & 1)*16 + rr;
  int csrc = c ^ (lc & 7);
  const float* src = (dir ? wb : wf) + (size_t)gcol*512 + csrc*8;
  float4 f0 = *(const float4*)src;
  float4 f1 = *(const float4*)(src + 4);
  uint32_t p0 = (uint32_t)f2bf_bits(f0.x) | ((uint32_t)f2bf_bits(f0.y) << 16);
  uint32_t p1 = (uint32_t)f2bf_bits(f0.z) | ((uint32_t)f2bf_bits(f0.w) << 16);
  uint32_t p2 = (uint32_t)f2bf_bits(f1.x) | ((uint32_t)f2bf_bits(f1.y) << 16);
  uint32_t p3 = (uint32_t)f2bf_bits(f1.z) | ((uint32_t)f2bf_bits(f1.w) << 16);
  wmem[idx] = make_uint4(p0,p1,p2,p3);
}

// ---------------------------------------------------------------- GEMM: xp = emb @ Wcat^T + bias
// OUTPUT BLOCKED for k_recur: xp[dir][t][bg][member][g][16 rows][32 cols] bf16
__launch_bounds__(256)
__global__ void k_gemm_xp(const uint16_t* __restrict__ A, const uint16_t* __restrict__ Bw,
                          const float* __restrict__ bihf, const float* __restrict__ bihb,
                          uint16_t* __restrict__ C)
{
  __shared__ uint16_t lA[2][128*32];
  __shared__ uint16_t lB[2][128*32];
  const int K = 1024;
  int bn = blockIdx.x, bm = blockIdx.y;
  int tid = threadIdx.x;
  int lane = tid & 63, wid = tid >> 6;
  int wm = wid >> 1, wn = wid & 1;
  int rowBase = bm*128, colBase = bn*128;
  int rg = lane >> 4, rr = lane & 15;

  auto stage = [&](int buf, int kt){
    #pragma unroll
    for(int i=0;i<2;i++){
      int e = (i*256 + tid)*8;
      int r = e >> 5, c = e & 31;
      __builtin_amdgcn_global_load_lds((const GLOBAL_AS void*)(A + (size_t)(rowBase + r)*K + kt*32 + c),
                                       (LDS_AS void*)&lA[buf][e], 16, 0, 0);
    }
    #pragma unroll
    for(int i=0;i<2;i++){
      int e = (i*256 + tid)*8;
      int r = e >> 5, c = e & 31;
      __builtin_amdgcn_global_load_lds((const GLOBAL_AS void*)(Bw + (size_t)(colBase + r)*K + kt*32 + c),
                                       (LDS_AS void*)&lB[buf][e], 16, 0, 0);
    }
  };

  f32x4 acc[4][4];
  #pragma unroll
  for(int mi=0;mi<4;mi++)
    #pragma unroll
    for(int ni=0;ni<4;ni++) acc[mi][ni] = (f32x4){0.f,0.f,0.f,0.f};

  stage(0, 0);
  __syncthreads();
  for(int kt=0; kt<32; kt++){
    int buf = kt & 1;
    if(kt+1 < 32) stage(buf^1, kt+1);
    bf16x8 af[4], bfv[4];
    #pragma unroll
    for(int mi=0;mi<4;mi++)
      af[mi] = *(const bf16x8*)&lA[buf][(wm*64 + mi*16 + rr)*32 + rg*8];
    #pragma unroll
    for(int ni=0;ni<4;ni++)
      bfv[ni] = *(const bf16x8*)&lB[buf][(wn*64 + ni*16 + rr)*32 + rg*8];
    #pragma unroll
    for(int mi=0;mi<4;mi++)
      #pragma unroll
      for(int ni=0;ni<4;ni++)
        acc[mi][ni] = __builtin_amdgcn_mfma_f32_16x16x32_bf16(af[mi], bfv[ni], acc[mi][ni], 0,0,0);
    __syncthreads();
  }

  #pragma unroll
  for(int ni=0;ni<4;ni++){
    int col = colBase + wn*64 + ni*16 + rr;
    float bv = (col < G3) ? bihf[col] : bihb[col - G3];
    int dircol = (col >= G3) ? 1 : 0;
    int cm = col - dircol*G3;
    int g  = cm >> 9;
    int j  = cm & 511;
    int mem = j >> 5, cc = j & 31;
    #pragma unroll
    for(int mi=0;mi<4;mi++){
      int row0 = rowBase + wm*64 + mi*16 + rg*4;
      int tt = row0 >> 6;
      int b0 = row0 & 63;
      int bgx = b0 >> 4, rr0 = b0 & 15;
      size_t ob = (((((size_t)dircol*512 + tt)*4 + bgx)*16 + mem)*3 + g)*512 + rr0*32 + cc;
      C[ob]      = f2bf_bits(acc[mi][ni][0]+bv);
      C[ob+32]   = f2bf_bits(acc[mi][ni][1]+bv);
      C[ob+64]   = f2bf_bits(acc[mi][ni][2]+bv);
      C[ob+96]   = f2bf_bits(acc[mi][ni][3]+bv);
    }
  }
}

// ---------------------------------------------------------------- GEMM: attention, fused tanh + ctx_w dot
__launch_bounds__(256)
__global__ void k_gemm_att(const uint16_t* __restrict__ A, const uint16_t* __restrict__ Bw,
                           const float* __restrict__ attn_b, const float* __restrict__ ctx_w,
                           float* __restrict__ scores_raw)
{
  __shared__ uint16_t lA[2][128*32];
  __shared__ uint16_t lB[2][128*32];
  const int K = 1024;
  int bn = blockIdx.x, bm = blockIdx.y;
  int tid = threadIdx.x;
  int lane = tid & 63, wid = tid >> 6;
  int wm = wid >> 1, wn = wid & 1;
  int rowBase = bm*128, colBase = bn*128;
  int rg = lane >> 4, rr = lane & 15;

  auto stage = [&](int buf, int kt){
    #pragma unroll
    for(int i=0;i<2;i++){
      int e = (i*256 + tid)*8;
      int r = e >> 5, c = e & 31;
      __builtin_amdgcn_global_load_lds((const GLOBAL_AS void*)(A + (size_t)(rowBase + r)*K + kt*32 + c),
                                       (LDS_AS void*)&lA[buf][e], 16, 0, 0);
    }
    #pragma unroll
    for(int i=0;i<2;i++){
      int e = (i*256 + tid)*8;
      int r = e >> 5, c = e & 31;
      __builtin_amdgcn_global_load_lds((const GLOBAL_AS void*)(Bw + (size_t)(colBase + r)*K + kt*32 + c),
                                       (LDS_AS void*)&lB[buf][e], 16, 0, 0);
    }
  };

  f32x4 acc[4][4];
  #pragma unroll
  for(int mi=0;mi<4;mi++)
    #pragma unroll
    for(int ni=0;ni<4;ni++) acc[mi][ni] = (f32x4){0.f,0.f,0.f,0.f};

  stage(0, 0);
  __syncthreads();
  for(int kt=0; kt<32; kt++){
    int buf = kt & 1;
    if(kt+1 < 32) stage(buf^1, kt+1);
    bf16x8 af[4], bfv[4];
    #pragma unroll
    for(int mi=0;mi<4;mi++)
      af[mi] = *(const bf16x8*)&lA[buf][(wm*64 + mi*16 + rr)*32 + rg*8];
    #pragma unroll
    for(int ni=0;ni<4;ni++)
      bfv[ni] = *(const bf16x8*)&lB[buf][(wn*64 + ni*16 + rr)*32 + rg*8];
    #pragma unroll
    for(int mi=0;mi<4;mi++)
      #pragma unroll
      for(int ni=0;ni<4;ni++)
        acc[mi][ni] = __builtin_amdgcn_mfma_f32_16x16x32_bf16(af[mi], bfv[ni], acc[mi][ni], 0,0,0);
    __syncthreads();
  }

  float ab[4], cw[4];
  #pragma unroll
  for(int ni=0;ni<4;ni++){
    int col = colBase + wn*64 + ni*16 + rr;
    ab[ni] = attn_b[col];
    cw[ni] = ctx_w[col];
  }
  #pragma unroll
  for(int mi=0;mi<4;mi++){
    #pragma unroll
    for(int r=0;r<4;r++){
      float part = 0.f;
      #pragma unroll
      for(int ni=0;ni<4;ni++) part += tanhf(acc[mi][ni][r] + ab[ni]) * cw[ni];
      #pragma unroll
      for(int off=1; off<16; off<<=1) part += __shfl_xor(part, off);
      if(rr == 0){
        int row = rowBase + wm*64 + mi*16 + rg*4 + r;
        atomicAdd(&scores_raw[row], part);
      }
    }
  }
}

// ---------------------------------------------------------------- recurrence v7: v6 protocol, shorter critical path.
// All-wave polling (no poll barrier); 8-wave h staging (4 independent LLC loads/lane);
// blocked xp (3 coalesced 1KB loads/step). 3 barriers/step.
__launch_bounds__(768, 3)
__global__ void k_recur(const uint16_t* __restrict__ xp,     // blocked [dir][T][bg][member][3][16][32]
                        const uint4* __restrict__ wmem,      // pre-swizzled W slices
                        const float* __restrict__ bhhf, const float* __restrict__ bhhb,
                        uint16_t* __restrict__ hpub,         // [2][2][64][512] bf16
                        unsigned* __restrict__ flags,        // [8][16]
                        uint16_t* __restrict__ f_out)
{
  __shared__ uint16_t Wl[96*512];        // 96 KB
  __shared__ uint16_t hl[16*512];        // 16 KB, chunk-XOR swizzled
  __shared__ float    ghl[2*6*16*17];    // 12.75 KB

  int bid = blockIdx.x;
  int dir = bid & 1, bg = (bid >> 1) & 3, member = bid >> 3;
  int chain = bid & 7;
  int jb = member*32;
  int tid = threadIdx.x;
  int lane = tid & 63, w = tid >> 6;
  int rr = lane & 15, rg = lane >> 4;
  int ct = w >> 1, kh = w & 1;

  // stage W slice: linear global_load_lds (layout pre-swizzled by k_conv_whh)
  const uint4* wsrc = wmem + (size_t)(dir*16 + member)*6144;
  for(int e = tid; e < 6144; e += 768)
    __builtin_amdgcn_global_load_lds((const GLOBAL_AS void*)(wsrc + e),
                                     (LDS_AS void*)&Wl[e*8], 16, 0, 0);
  for(int i = tid; i < 2*6*16*17; i += 768) ghl[i] = 0.f;

  // gate-thread constants: thread (tid<512) owns (row=tid>>5, col=tid&31)
  int gcol = tid & 31;
  const float* bhh = dir ? bhhb : bhhf;
  float bR = 0.f, bZ = 0.f, bN = 0.f, hprev = 0.f;
  if(tid < 512){
    bR = bhh[jb + gcol];
    bZ = bhh[512 + jb + gcol];
    bN = bhh[1024 + jb + gcol];
  }

  // staging role (waves 0..7): row sr, 2 non-adjacent swizzled chunks
  int sr  = w*2 + (lane >> 5);     // 0..15
  int slr = lane & 31;
  int sc0 = slr ^ (sr & 7);        // dest chunk; +32 for second

  __syncthreads();   // W staged (barrier drains vmcnt), ghl zeroed

  #pragma unroll 1
  for(int t = 0; t < 512; t++){
    int trow = dir ? (511 - t) : t;

    // xp loads: 3 coalesced 1KB loads (blocked layout); consumed after 2 barriers
    uint16_t xr16 = 0, xz16 = 0, xn16 = 0;
    if(tid < 512){
      const uint16_t* xb = xp + (((((size_t)dir*512 + trow)*4 + bg)*16 + member)*3)*512;
      xr16 = xb[tid];
      xz16 = xb[512 + tid];
      xn16 = xb[1024 + tid];
    }

    if(t > 0){
      // all waves poll the 16 member flags (no barrier after)
      {
        const unsigned* fl = flags + chain*16;
        bool idle = (lane >= 16);
        while(true){
          bool ok = idle ||
            (__hip_atomic_load(&fl[lane & 15], __ATOMIC_RELAXED, __HIP_MEMORY_SCOPE_AGENT) >= (unsigned)t);
          if(__all(ok)) break;
          __builtin_amdgcn_s_sleep(1);
        }
      }
      // stage h: waves 0-7, 4 independent LLC loads/lane
      if(w < 8){
        const unsigned long long* hs =
          (const unsigned long long*)(hpub + (size_t)((dir*2 + (t & 1))*64 + bg*16)*512);
        unsigned long long a0 = __hip_atomic_load(hs + sr*128 + 2*slr,      __ATOMIC_RELAXED, __HIP_MEMORY_SCOPE_AGENT);
        unsigned long long a1 = __hip_atomic_load(hs + sr*128 + 2*slr + 1,  __ATOMIC_RELAXED, __HIP_MEMORY_SCOPE_AGENT);
        unsigned long long b0 = __hip_atomic_load(hs + sr*128 + 64 + 2*slr, __ATOMIC_RELAXED, __HIP_MEMORY_SCOPE_AGENT);
        unsigned long long b1 = __hip_atomic_load(hs + sr*128 + 65 + 2*slr, __ATOMIC_RELAXED, __HIP_MEMORY_SCOPE_AGENT);
        union{ unsigned long long q[2]; uint4 v; } u0, u1;
        u0.q[0] = a0; u0.q[1] = a1;
        u1.q[0] = b0; u1.q[1] = b1;
        *(uint4*)&hl[sr*512 + sc0*8]        = u0.v;
        *(uint4*)&hl[sr*512 + (sc0+32)*8]   = u1.v;
      }
    }
    __syncthreads();   // (A) hl ready

    if(t > 0){
      // gh partial: wave (ct, kh): 16 rows x 16 cols over K-half kh
      f32x4 acc = (f32x4){0.f,0.f,0.f,0.f};
      #pragma unroll
      for(int ks = 0; ks < 8; ks++){
        int ch = kh*32 + ks*4 + rg;
        int sw = (ch ^ (rr & 7))*8;
        bf16x8 a = *(const bf16x8*)&hl[rr*512 + sw];
        bf16x8 b = *(const bf16x8*)&Wl[(ct*16 + rr)*512 + sw];
        acc = __builtin_amdgcn_mfma_f32_16x16x32_bf16(a, b, acc, 0,0,0);
      }
      #pragma unroll
      for(int j = 0; j < 4; j++)
        ghl[((kh*6 + ct)*16 + rg*4 + j)*17 + rr] = acc[j];
    }
    __syncthreads();   // (B) ghl ready (zeros at t==0)

    // gates
    if(tid < 512){
      int grow = tid >> 5;
      int c16 = gcol >> 4, cc = gcol & 15;
      float gR = ghl[((0 + c16)*16 + grow)*17 + cc] + ghl[((6  + c16)*16 + grow)*17 + cc] + bR;
      float gZ = ghl[((2 + c16)*16 + grow)*17 + cc] + ghl[((8  + c16)*16 + grow)*17 + cc] + bZ;
      float gN = ghl[((4 + c16)*16 + grow)*17 + cc] + ghl[((10 + c16)*16 + grow)*17 + cc] + bN;
      float rv = sig_f(bf2f_bits(xr16) + gR);
      float zv = sig_f(bf2f_bits(xz16) + gZ);
      float nv = tanh_f(bf2f_bits(xn16) + rv*gN);
      float hnew = (1.f - zv)*nv + zv*hprev;
      hprev = hnew;
      unsigned hb = (unsigned)f2bf_bits(hnew);
      unsigned nb = (unsigned)__shfl_down((int)hb, 1);
      if((tid & 1) == 0){
        unsigned pk = hb | (nb << 16);
        __hip_atomic_store(
          (unsigned*)(hpub + (size_t)((dir*2 + ((t+1) & 1))*64 + bg*16 + grow)*512 + jb + gcol),
          pk, __ATOMIC_RELAXED, __HIP_MEMORY_SCOPE_AGENT);
        *(unsigned*)&f_out[((size_t)trow*64 + bg*16 + grow)*1024 + dir*512 + jb + gcol] = pk;
      }
    }
    __syncthreads();   // (C) barrier drains vmcnt(0): publishes acked at LLC
    if(tid == 0)
      __hip_atomic_store(&flags[chain*16 + member], (unsigned)(t+1),
                         __ATOMIC_RELAXED, __HIP_MEMORY_SCOPE_AGENT);
  }
}

// ---------------------------------------------------------------- softmax over T per batch
__global__ void k_softmax(const float* __restrict__ scores_raw, float* __restrict__ wsm){
  __shared__ float sv[512];
  __shared__ float red[8];
  int b = blockIdx.x;
  int tid = threadIdx.x;
  float mymax = -1e30f;
  for(int t = tid; t < 512; t += 256){
    float s = tanhf(scores_raw[t*64 + b]);
    sv[t] = s;
    mymax = fmaxf(mymax, s);
  }
  #pragma unroll
  for(int off=1; off<64; off<<=1) mymax = fmaxf(mymax, __shfl_xor(mymax, off));
  if((tid&63)==0) red[tid>>6] = mymax;
  __syncthreads();
  float bmax = fmaxf(fmaxf(red[0],red[1]), fmaxf(red[2],red[3]));
  __syncthreads();
  float mysum = 0.f;
  for(int t = tid; t < 512; t += 256){
    float e = __expf(sv[t] - bmax);
    sv[t] = e;
    mysum += e;
  }
  #pragma unroll
  for(int off=1; off<64; off<<=1) mysum += __shfl_xor(mysum, off);
  if((tid&63)==0) red[tid>>6] = mysum;
  __syncthreads();
  float inv = 1.f/(red[0]+red[1]+red[2]+red[3]);
  for(int t = tid; t < 512; t += 256) wsm[b*512 + t] = sv[t]*inv;
}

// ---------------------------------------------------------------- ctx[b,d] = sum_t w[b,t] f[t,b,d]
__global__ void k_ctx(const uint16_t* __restrict__ f_out, const float* __restrict__ wsm, float* __restrict__ ctx){
  __shared__ float wloc[512];
  int b = blockIdx.x >> 2, chunk = blockIdx.x & 3;
  int tid = threadIdx.x;
  for(int t = tid; t < 512; t += 256) wloc[t] = wsm[b*512 + t];
  __syncthreads();
  int d = chunk*256 + tid;
  float acc = 0.f;
  #pragma unroll 8
  for(int t = 0; t < 512; t++)
    acc += wloc[t] * bf2f_bits(f_out[(size_t)(t*64 + b)*1024 + d]);
  ctx[b*1024 + d] = acc;
}

// ---------------------------------------------------------------- classifier
__global__ void k_cls1(const float* __restrict__ ctx, const float* __restrict__ w1,
                       const float* __restrict__ b1, float* __restrict__ hid){
  int idx = blockIdx.x*256 + threadIdx.x;   // 32768
  int b = idx >> 9, h = idx & 511;
  float acc = b1[h];
  for(int d = 0; d < 1024; d++) acc += ctx[b*1024 + d] * w1[d*512 + h];
  hid[idx] = fmaxf(acc, 0.f);
}

__global__ void k_cls2(const float* __restrict__ hid, const float* __restrict__ w2,
                       const float* __restrict__ b2, float* __restrict__ out){
  int idx = threadIdx.x;   // 640
  if(idx >= 640) return;
  int b = idx / 10, o = idx % 10;
  float acc = b2[o];
  for(int h = 0; h < 512; h++) acc += hid[b*512 + h] * w2[h*10 + o];
  out[idx] = acc;
}

// ---------------------------------------------------------------- launch
extern "C" void kernel_launch(void* const* d_in, const int* in_sizes, int n_in,
                              void* d_out, int out_size, void* d_ws, size_t ws_size,
                              hipStream_t stream)
{
  const float* emb    = (const float*)d_in[1];
  const float* w_ih_f = (const float*)d_in[2];
  const float* w_hh_f = (const float*)d_in[3];
  const float* b_ih_f = (const float*)d_in[4];
  const float* b_hh_f = (const float*)d_in[5];
  const float* w_ih_b = (const float*)d_in[6];
  const float* w_hh_b = (const float*)d_in[7];
  const float* b_ih_b = (const float*)d_in[8];
  const float* b_hh_b = (const float*)d_in[9];
  const float* attn_w = (const float*)d_in[10];
  const float* attn_b = (const float*)d_in[11];
  const float* ctx_w  = (const float*)d_in[12];
  const float* cls_w1 = (const float*)d_in[13];
  const float* cls_b1 = (const float*)d_in[14];
  const float* cls_w2 = (const float*)d_in[15];
  const float* cls_b2 = (const float*)d_in[16];
  float* out = (float*)d_out;

  char* ws = (char*)d_ws;
  size_t off = 0;
  auto alloc = [&](size_t bytes){ void* p = ws + off; off += (bytes + 255) & ~(size_t)255; return p; };
  uint16_t* femb = (uint16_t*)alloc((size_t)MROWS*DIN*2);      // emb bf16, later overlaid by f_out
  uint16_t* wcat = (uint16_t*)alloc((size_t)NC*DIN*2);
  uint16_t* xp   = (uint16_t*)alloc((size_t)MROWS*NC*2);       // blocked layout
  uint16_t* awT  = (uint16_t*)alloc((size_t)1024*1024*2);
  uint4*    wmem = (uint4*)alloc((size_t)2*16*96*64*16);       // 3 MB pre-swizzled W
  uint16_t* hpub = (uint16_t*)alloc((size_t)2*2*64*512*2);     // 256 KB
  unsigned* flags= (unsigned*)alloc(4096);
  float* scraw   = (float*)alloc((size_t)MROWS*4);
  float* wsm     = (float*)alloc((size_t)B_*T_*4);
  float* ctx     = (float*)alloc((size_t)B_*1024*4);
  float* hid     = (float*)alloc((size_t)B_*512*4);

  hipMemsetAsync(flags, 0, 4096, stream);
  hipMemsetAsync(scraw, 0, (size_t)MROWS*4, stream);

  k_conv_emb<<<16384, 256, 0, stream>>>(emb, femb, (long)MROWS*DIN/8);
  k_conv_wcat<<<12288, 256, 0, stream>>>(w_ih_f, w_ih_b, wcat, NC*DIN);
  k_conv_awt<<<4096, 256, 0, stream>>>(attn_w, awT, 1024*1024);
  k_conv_whh<<<768, 256, 0, stream>>>(w_hh_f, w_hh_b, wmem);

  k_gemm_xp<<<dim3(24,256), 256, 0, stream>>>(femb, wcat, b_ih_f, b_ih_b, xp);

  k_recur<<<128, 768, 0, stream>>>(xp, wmem, b_hh_f, b_hh_b, hpub, flags, femb /* = f_out */);

  k_gemm_att<<<dim3(8,256), 256, 0, stream>>>(femb, awT, attn_b, ctx_w, scraw);
  k_softmax<<<64, 256, 0, stream>>>(scraw, wsm);
  k_ctx<<<256, 256, 0, stream>>>(femb, wsm, ctx);
  k_cls1<<<128, 256, 0, stream>>>(ctx, cls_w1, cls_b1, hid);
  k_cls2<<<1, 640, 0, stream>>>(hid, cls_w2, cls_b2, out);
}

// Round 9
// 1719.989 us; speedup vs baseline: 13.8344x; 1.1332x over previous
//
#include <hip/hip_runtime.h>
#include <stdint.h>

// Problem constants
#define T_   512
#define B_   64
#define DIN  1024
#define HID  512
#define G3   1536     // 3*HID
#define NC   3072     // both dirs of gates
#define MROWS 32768   // T_*B_

typedef __bf16 bf16;
typedef __bf16 bf16x8 __attribute__((ext_vector_type(8)));
typedef float  f32x4  __attribute__((ext_vector_type(4)));

#define GLOBAL_AS __attribute__((address_space(1)))
#define LDS_AS    __attribute__((address_space(3)))

__device__ __forceinline__ uint16_t f2bf_bits(float x){
  union{float f; uint32_t u;} v; v.f = x;
  uint32_t u = v.u;
  u += 0x7FFFu + ((u >> 16) & 1u);   // round-to-nearest-even
  return (uint16_t)(u >> 16);
}
__device__ __forceinline__ float bf2f_bits(uint16_t h){
  union{uint32_t u; float f;} v; v.u = ((uint32_t)h) << 16;
  return v.f;
}
__device__ __forceinline__ float sig_f(float x){
  return 1.f/(1.f + __expf(-x));
}
__device__ __forceinline__ float tanh_f(float x){
  return 1.f - 2.f/(1.f + __expf(2.f*x));
}

// ---------------------------------------------------------------- converts
__global__ void k_conv_emb(const float* __restrict__ src, uint16_t* __restrict__ dst, long n8){
  long i = (long)blockIdx.x*blockDim.x + threadIdx.x;
  if(i >= n8) return;
  const float4* s = (const float4*)src;
  float4 a = s[i*2], b = s[i*2+1];
  uint32_t p0 = (uint32_t)f2bf_bits(a.x) | ((uint32_t)f2bf_bits(a.y) << 16);
  uint32_t p1 = (uint32_t)f2bf_bits(a.z) | ((uint32_t)f2bf_bits(a.w) << 16);
  uint32_t p2 = (uint32_t)f2bf_bits(b.x) | ((uint32_t)f2bf_bits(b.y) << 16);
  uint32_t p3 = (uint32_t)f2bf_bits(b.z) | ((uint32_t)f2bf_bits(b.w) << 16);
  ((uint4*)dst)[i] = make_uint4(p0,p1,p2,p3);
}

__global__ void k_conv_wcat(const float* __restrict__ wf, const float* __restrict__ wb, uint16_t* __restrict__ dst, int n){
  int i = blockIdx.x*256 + threadIdx.x;
  if(i >= n) return;
  float v = (i < G3*DIN) ? wf[i] : wb[i - G3*DIN];
  dst[i] = f2bf_bits(v);
}

__global__ void k_conv_awt(const float* __restrict__ aw, uint16_t* __restrict__ dst, int n){
  int i = blockIdx.x*256 + threadIdx.x;
  if(i >= n) return;
  int e = i >> 10, d = i & 1023;
  dst[i] = f2bf_bits(aw[d*1024 + e]);   // transpose: awT[e][d]
}

// W_hh -> bf16, member-sliced, chunk-XOR-pre-swizzled so k_recur's
// global_load_lds is linear and ds_reads are bank-conflict-free.
__global__ void k_conv_whh(const float* __restrict__ wf, const float* __restrict__ wb, uint4* __restrict__ wmem){
  int idx = blockIdx.x*256 + threadIdx.x;   // 196608 total
  if(idx >= 2*16*96*64) return;
  int c  = idx & 63;
  int t2 = idx >> 6;
  int lc = t2 % 96;
  int t3 = t2 / 96;
  int member = t3 & 15, dir = t3 >> 4;
  int ct = lc >> 4, rr = lc & 15;
  int gcol = (ct >> 1)*512 + member*32 + (ct & 1)*16 + rr;
  int csrc = c ^ (lc & 7);
  const float* src = (dir ? wb : wf) + (size_t)gcol*512 + csrc*8;
  float4 f0 = *(const float4*)src;
  float4 f1 = *(const float4*)(src + 4);
  uint32_t p0 = (uint32_t)f2bf_bits(f0.x) | ((uint32_t)f2bf_bits(f0.y) << 16);
  uint32_t p1 = (uint32_t)f2bf_bits(f0.z) | ((uint32_t)f2bf_bits(f0.w) << 16);
  uint32_t p2 = (uint32_t)f2bf_bits(f1.x) | ((uint32_t)f2bf_bits(f1.y) << 16);
  uint32_t p3 = (uint32_t)f2bf_bits(f1.z) | ((uint32_t)f2bf_bits(f1.w) << 16);
  wmem[idx] = make_uint4(p0,p1,p2,p3);
}

// ---------------------------------------------------------------- GEMM: xp = emb @ Wcat^T + bias
// OUTPUT BLOCKED for k_recur: xp[dir][t][bg][member][g][16 rows][32 cols] bf16
__launch_bounds__(256)
__global__ void k_gemm_xp(const uint16_t* __restrict__ A, const uint16_t* __restrict__ Bw,
                          const float* __restrict__ bihf, const float* __restrict__ bihb,
                          uint16_t* __restrict__ C)
{
  __shared__ uint16_t lA[2][128*32];
  __shared__ uint16_t lB[2][128*32];
  const int K = 1024;
  int bn = blockIdx.x, bm = blockIdx.y;
  int tid = threadIdx.x;
  int lane = tid & 63, wid = tid >> 6;
  int wm = wid >> 1, wn = wid & 1;
  int rowBase = bm*128, colBase = bn*128;
  int rg = lane >> 4, rr = lane & 15;

  auto stage = [&](int buf, int kt){
    #pragma unroll
    for(int i=0;i<2;i++){
      int e = (i*256 + tid)*8;
      int r = e >> 5, c = e & 31;
      __builtin_amdgcn_global_load_lds((const GLOBAL_AS void*)(A + (size_t)(rowBase + r)*K + kt*32 + c),
                                       (LDS_AS void*)&lA[buf][e], 16, 0, 0);
    }
    #pragma unroll
    for(int i=0;i<2;i++){
      int e = (i*256 + tid)*8;
      int r = e >> 5, c = e & 31;
      __builtin_amdgcn_global_load_lds((const GLOBAL_AS void*)(Bw + (size_t)(colBase + r)*K + kt*32 + c),
                                       (LDS_AS void*)&lB[buf][e], 16, 0, 0);
    }
  };

  f32x4 acc[4][4];
  #pragma unroll
  for(int mi=0;mi<4;mi++)
    #pragma unroll
    for(int ni=0;ni<4;ni++) acc[mi][ni] = (f32x4){0.f,0.f,0.f,0.f};

  stage(0, 0);
  __syncthreads();
  for(int kt=0; kt<32; kt++){
    int buf = kt & 1;
    if(kt+1 < 32) stage(buf^1, kt+1);
    bf16x8 af[4], bfv[4];
    #pragma unroll
    for(int mi=0;mi<4;mi++)
      af[mi] = *(const bf16x8*)&lA[buf][(wm*64 + mi*16 + rr)*32 + rg*8];
    #pragma unroll
    for(int ni=0;ni<4;ni++)
      bfv[ni] = *(const bf16x8*)&lB[buf][(wn*64 + ni*16 + rr)*32 + rg*8];
    #pragma unroll
    for(int mi=0;mi<4;mi++)
      #pragma unroll
      for(int ni=0;ni<4;ni++)
        acc[mi][ni] = __builtin_amdgcn_mfma_f32_16x16x32_bf16(af[mi], bfv[ni], acc[mi][ni], 0,0,0);
    __syncthreads();
  }

  #pragma unroll
  for(int ni=0;ni<4;ni++){
    int col = colBase + wn*64 + ni*16 + rr;
    float bv = (col < G3) ? bihf[col] : bihb[col - G3];
    int dircol = (col >= G3) ? 1 : 0;
    int cm = col - dircol*G3;
    int g  = cm >> 9;
    int j  = cm & 511;
    int mem = j >> 5, cc = j & 31;
    #pragma unroll
    for(int mi=0;mi<4;mi++){
      int row0 = rowBase + wm*64 + mi*16 + rg*4;
      int tt = row0 >> 6;
      int b0 = row0 & 63;
      int bgx = b0 >> 4, rr0 = b0 & 15;
      size_t ob = (((((size_t)dircol*512 + tt)*4 + bgx)*16 + mem)*3 + g)*512 + rr0*32 + cc;
      C[ob]      = f2bf_bits(acc[mi][ni][0]+bv);
      C[ob+32]   = f2bf_bits(acc[mi][ni][1]+bv);
      C[ob+64]   = f2bf_bits(acc[mi][ni][2]+bv);
      C[ob+96]   = f2bf_bits(acc[mi][ni][3]+bv);
    }
  }
}

// ---------------------------------------------------------------- GEMM: attention, fused tanh + ctx_w dot
__launch_bounds__(256)
__global__ void k_gemm_att(const uint16_t* __restrict__ A, const uint16_t* __restrict__ Bw,
                           const float* __restrict__ attn_b, const float* __restrict__ ctx_w,
                           float* __restrict__ scores_raw)
{
  __shared__ uint16_t lA[2][128*32];
  __shared__ uint16_t lB[2][128*32];
  const int K = 1024;
  int bn = blockIdx.x, bm = blockIdx.y;
  int tid = threadIdx.x;
  int lane = tid & 63, wid = tid >> 6;
  int wm = wid >> 1, wn = wid & 1;
  int rowBase = bm*128, colBase = bn*128;
  int rg = lane >> 4, rr = lane & 15;

  auto stage = [&](int buf, int kt){
    #pragma unroll
    for(int i=0;i<2;i++){
      int e = (i*256 + tid)*8;
      int r = e >> 5, c = e & 31;
      __builtin_amdgcn_global_load_lds((const GLOBAL_AS void*)(A + (size_t)(rowBase + r)*K + kt*32 + c),
                                       (LDS_AS void*)&lA[buf][e], 16, 0, 0);
    }
    #pragma unroll
    for(int i=0;i<2;i++){
      int e = (i*256 + tid)*8;
      int r = e >> 5, c = e & 31;
      __builtin_amdgcn_global_load_lds((const GLOBAL_AS void*)(Bw + (size_t)(colBase + r)*K + kt*32 + c),
                                       (LDS_AS void*)&lB[buf][e], 16, 0, 0);
    }
  };

  f32x4 acc[4][4];
  #pragma unroll
  for(int mi=0;mi<4;mi++)
    #pragma unroll
    for(int ni=0;ni<4;ni++) acc[mi][ni] = (f32x4){0.f,0.f,0.f,0.f};

  stage(0, 0);
  __syncthreads();
  for(int kt=0; kt<32; kt++){
    int buf = kt & 1;
    if(kt+1 < 32) stage(buf^1, kt+1);
    bf16x8 af[4], bfv[4];
    #pragma unroll
    for(int mi=0;mi<4;mi++)
      af[mi] = *(const bf16x8*)&lA[buf][(wm*64 + mi*16 + rr)*32 + rg*8];
    #pragma unroll
    for(int ni=0;ni<4;ni++)
      bfv[ni] = *(const bf16x8*)&lB[buf][(wn*64 + ni*16 + rr)*32 + rg*8];
    #pragma unroll
    for(int mi=0;mi<4;mi++)
      #pragma unroll
      for(int ni=0;ni<4;ni++)
        acc[mi][ni] = __builtin_amdgcn_mfma_f32_16x16x32_bf16(af[mi], bfv[ni], acc[mi][ni], 0,0,0);
    __syncthreads();
  }

  float ab[4], cw[4];
  #pragma unroll
  for(int ni=0;ni<4;ni++){
    int col = colBase + wn*64 + ni*16 + rr;
    ab[ni] = attn_b[col];
    cw[ni] = ctx_w[col];
  }
  #pragma unroll
  for(int mi=0;mi<4;mi++){
    #pragma unroll
    for(int r=0;r<4;r++){
      float part = 0.f;
      #pragma unroll
      for(int ni=0;ni<4;ni++) part += tanhf(acc[mi][ni][r] + ab[ni]) * cw[ni];
      #pragma unroll
      for(int off=1; off<16; off<<=1) part += __shfl_xor(part, off);
      if(rr == 0){
        int row = rowBase + wm*64 + mi*16 + rg*4 + r;
        atomicAdd(&scores_raw[row], part);
      }
    }
  }
}

// ---------------------------------------------------------------- recurrence v9: tag-in-data transport.
// h published as u64 {data32 = 2 bf16 | tag32 = t+1} agent-relaxed atomics (LLC).
// Consumer's tagged load IS the sync: retry slots whose tag != t (exact equality).
// No flags, no drains; 2 barriers/step. tagbuf memset(0) per launch (replay-safe).
// tagbuf layout: [dir][par][bg][row 16][slot 256] u64, slot = col>>1.
__launch_bounds__(768, 3)
__global__ void k_recur(const uint16_t* __restrict__ xp,     // blocked [dir][T][bg][member][3][16][32]
                        const uint4* __restrict__ wmem,      // pre-swizzled W slices
                        const float* __restrict__ bhhf, const float* __restrict__ bhhb,
                        unsigned long long* __restrict__ tagbuf,
                        uint16_t* __restrict__ f_out)
{
  __shared__ uint16_t Wl[96*512];        // 96 KB
  __shared__ uint16_t hl[16*512];        // 16 KB, chunk-XOR swizzled
  __shared__ float    ghl[2*6*16*17];    // 12.75 KB

  int bid = blockIdx.x;
  int dir = bid & 1, bg = (bid >> 1) & 3, member = bid >> 3;
  int jb = member*32;
  int tid = threadIdx.x;
  int lane = tid & 63, w = tid >> 6;
  int rr = lane & 15, rg = lane >> 4;
  int ct = w >> 1, kh = w & 1;

  // stage W slice: linear global_load_lds (layout pre-swizzled by k_conv_whh)
  const uint4* wsrc = wmem + (size_t)(dir*16 + member)*6144;
  for(int e = tid; e < 6144; e += 768)
    __builtin_amdgcn_global_load_lds((const GLOBAL_AS void*)(wsrc + e),
                                     (LDS_AS void*)&Wl[e*8], 16, 0, 0);
  for(int i = tid; i < 2*6*16*17; i += 768) ghl[i] = 0.f;

  // gate-thread constants: thread (tid<512) owns (row=tid>>5, col=jb+(tid&31))
  int gcol = tid & 31;
  const float* bhh = dir ? bhhb : bhhf;
  float bR = 0.f, bZ = 0.f, bN = 0.f, hprev = 0.f;
  if(tid < 512){
    bR = bhh[jb + gcol];
    bZ = bhh[512 + jb + gcol];
    bN = bhh[1024 + jb + gcol];
  }

  // consumer staging role (waves 0..7 = tid<512): row, 8 slots (stride 32)
  int srow = tid >> 5;
  int sbase = tid & 31;                   // slot base; slots sbase+32k
  int cswz = ((sbase >> 2) ^ (srow & 7)); // swizzled chunk base (sbase>>2 in 0..7)
  int lpos0 = srow*512 + cswz*8 + (sbase & 3)*2;

  __syncthreads();   // W staged (drains vmcnt), ghl zeroed

  #pragma unroll 1
  for(int t = 0; t < 512; t++){
    int trow = dir ? (511 - t) : t;

    // xp loads: 3 coalesced 1KB loads (blocked layout); consumed in gate phase
    uint16_t xr16 = 0, xz16 = 0, xn16 = 0;
    if(tid < 512){
      const uint16_t* xb = xp + (((((size_t)dir*512 + trow)*4 + bg)*16 + member)*3)*512;
      xr16 = xb[tid];
      xz16 = xb[512 + tid];
      xn16 = xb[1024 + tid];
    }

    if(t > 0 && tid < 512){
      // tagged h load: 8 slots, retry until tag == t
      const unsigned long long* tb =
        tagbuf + ((size_t)((dir*2 + ((t-1) & 1))*4 + bg)*16 + srow)*256 + sbase;
      unsigned want = (unsigned)t;
      unsigned long long v0,v1,v2,v3,v4,v5,v6,v7;
      v0 = __hip_atomic_load(tb +   0, __ATOMIC_RELAXED, __HIP_MEMORY_SCOPE_AGENT);
      v1 = __hip_atomic_load(tb +  32, __ATOMIC_RELAXED, __HIP_MEMORY_SCOPE_AGENT);
      v2 = __hip_atomic_load(tb +  64, __ATOMIC_RELAXED, __HIP_MEMORY_SCOPE_AGENT);
      v3 = __hip_atomic_load(tb +  96, __ATOMIC_RELAXED, __HIP_MEMORY_SCOPE_AGENT);
      v4 = __hip_atomic_load(tb + 128, __ATOMIC_RELAXED, __HIP_MEMORY_SCOPE_AGENT);
      v5 = __hip_atomic_load(tb + 160, __ATOMIC_RELAXED, __HIP_MEMORY_SCOPE_AGENT);
      v6 = __hip_atomic_load(tb + 192, __ATOMIC_RELAXED, __HIP_MEMORY_SCOPE_AGENT);
      v7 = __hip_atomic_load(tb + 224, __ATOMIC_RELAXED, __HIP_MEMORY_SCOPE_AGENT);
      bool o0 = ((unsigned)v0 == want), o1 = ((unsigned)v1 == want);
      bool o2 = ((unsigned)v2 == want), o3 = ((unsigned)v3 == want);
      bool o4 = ((unsigned)v4 == want), o5 = ((unsigned)v5 == want);
      bool o6 = ((unsigned)v6 == want), o7 = ((unsigned)v7 == want);
      while(!(o0 & o1 & o2 & o3 & o4 & o5 & o6 & o7)){
        if(!o0){ v0 = __hip_atomic_load(tb +   0, __ATOMIC_RELAXED, __HIP_MEMORY_SCOPE_AGENT); o0 = ((unsigned)v0 == want); }
        if(!o1){ v1 = __hip_atomic_load(tb +  32, __ATOMIC_RELAXED, __HIP_MEMORY_SCOPE_AGENT); o1 = ((unsigned)v1 == want); }
        if(!o2){ v2 = __hip_atomic_load(tb +  64, __ATOMIC_RELAXED, __HIP_MEMORY_SCOPE_AGENT); o2 = ((unsigned)v2 == want); }
        if(!o3){ v3 = __hip_atomic_load(tb +  96, __ATOMIC_RELAXED, __HIP_MEMORY_SCOPE_AGENT); o3 = ((unsigned)v3 == want); }
        if(!o4){ v4 = __hip_atomic_load(tb + 128, __ATOMIC_RELAXED, __HIP_MEMORY_SCOPE_AGENT); o4 = ((unsigned)v4 == want); }
        if(!o5){ v5 = __hip_atomic_load(tb + 160, __ATOMIC_RELAXED, __HIP_MEMORY_SCOPE_AGENT); o5 = ((unsigned)v5 == want); }
        if(!o6){ v6 = __hip_atomic_load(tb + 192, __ATOMIC_RELAXED, __HIP_MEMORY_SCOPE_AGENT); o6 = ((unsigned)v6 == want); }
        if(!o7){ v7 = __hip_atomic_load(tb + 224, __ATOMIC_RELAXED, __HIP_MEMORY_SCOPE_AGENT); o7 = ((unsigned)v7 == want); }
      }
      // LDS stage (chunk-XOR swizzled); slot s=sbase+32k -> chunk (cswz + 8k)
      *(uint32_t*)&hl[lpos0 +   0] = (uint32_t)(v0 >> 32);
      *(uint32_t*)&hl[lpos0 +  64] = (uint32_t)(v1 >> 32);
      *(uint32_t*)&hl[lpos0 + 128] = (uint32_t)(v2 >> 32);
      *(uint32_t*)&hl[lpos0 + 192] = (uint32_t)(v3 >> 32);
      *(uint32_t*)&hl[lpos0 + 256] = (uint32_t)(v4 >> 32);
      *(uint32_t*)&hl[lpos0 + 320] = (uint32_t)(v5 >> 32);
      *(uint32_t*)&hl[lpos0 + 384] = (uint32_t)(v6 >> 32);
      *(uint32_t*)&hl[lpos0 + 448] = (uint32_t)(v7 >> 32);
    }
    __syncthreads();   // (A) hl ready

    if(t > 0){
      // gh partial: wave (ct, kh): 16 rows x 16 cols over K-half kh
      f32x4 acc = (f32x4){0.f,0.f,0.f,0.f};
      #pragma unroll
      for(int ks = 0; ks < 8; ks++){
        int ch = kh*32 + ks*4 + rg;
        int sw = (ch ^ (rr & 7))*8;
        bf16x8 a = *(const bf16x8*)&hl[rr*512 + sw];
        bf16x8 b = *(const bf16x8*)&Wl[(ct*16 + rr)*512 + sw];
        acc = __builtin_amdgcn_mfma_f32_16x16x32_bf16(a, b, acc, 0,0,0);
      }
      #pragma unroll
      for(int j = 0; j < 4; j++)
        ghl[((kh*6 + ct)*16 + rg*4 + j)*17 + rr] = acc[j];
    }
    __syncthreads();   // (B) ghl ready (zeros at t==0)

    // gates + tagged publish
    if(tid < 512){
      int grow = tid >> 5;
      int c16 = gcol >> 4, cc = gcol & 15;
      float gR = ghl[((0 + c16)*16 + grow)*17 + cc] + ghl[((6  + c16)*16 + grow)*17 + cc] + bR;
      float gZ = ghl[((2 + c16)*16 + grow)*17 + cc] + ghl[((8  + c16)*16 + grow)*17 + cc] + bZ;
      float gN = ghl[((4 + c16)*16 + grow)*17 + cc] + ghl[((10 + c16)*16 + grow)*17 + cc] + bN;
      float rv = sig_f(bf2f_bits(xr16) + gR);
      float zv = sig_f(bf2f_bits(xz16) + gZ);
      float nv = tanh_f(bf2f_bits(xn16) + rv*gN);
      float hnew = (1.f - zv)*nv + zv*hprev;
      hprev = hnew;
      unsigned hb = (unsigned)f2bf_bits(hnew);
      unsigned nb = (unsigned)__shfl_down((int)hb, 1);
      if((tid & 1) == 0){
        unsigned pk = hb | (nb << 16);
        int slot = member*16 + (gcol >> 1);
        unsigned long long pv = ((unsigned long long)pk << 32) | (unsigned)(t + 1);
        __hip_atomic_store(
          tagbuf + ((size_t)((dir*2 + (t & 1))*4 + bg)*16 + grow)*256 + slot,
          pv, __ATOMIC_RELAXED, __HIP_MEMORY_SCOPE_AGENT);
        *(unsigned*)&f_out[((size_t)trow*64 + bg*16 + grow)*1024 + dir*512 + jb + gcol] = pk;
      }
    }
    // no drain barrier: next iteration's barriers cover LDS hazards; tag carries sync
  }
}

// ---------------------------------------------------------------- softmax over T per batch
__global__ void k_softmax(const float* __restrict__ scores_raw, float* __restrict__ wsm){
  __shared__ float sv[512];
  __shared__ float red[8];
  int b = blockIdx.x;
  int tid = threadIdx.x;
  float mymax = -1e30f;
  for(int t = tid; t < 512; t += 256){
    float s = tanhf(scores_raw[t*64 + b]);
    sv[t] = s;
    mymax = fmaxf(mymax, s);
  }
  #pragma unroll
  for(int off=1; off<64; off<<=1) mymax = fmaxf(mymax, __shfl_xor(mymax, off));
  if((tid&63)==0) red[tid>>6] = mymax;
  __syncthreads();
  float bmax = fmaxf(fmaxf(red[0],red[1]), fmaxf(red[2],red[3]));
  __syncthreads();
  float mysum = 0.f;
  for(int t = tid; t < 512; t += 256){
    float e = __expf(sv[t] - bmax);
    sv[t] = e;
    mysum += e;
  }
  #pragma unroll
  for(int off=1; off<64; off<<=1) mysum += __shfl_xor(mysum, off);
  if((tid&63)==0) red[tid>>6] = mysum;
  __syncthreads();
  float inv = 1.f/(red[0]+red[1]+red[2]+red[3]);
  for(int t = tid; t < 512; t += 256) wsm[b*512 + t] = sv[t]*inv;
}

// ---------------------------------------------------------------- ctx[b,d] = sum_t w[b,t] f[t,b,d]
__global__ void k_ctx(const uint16_t* __restrict__ f_out, const float* __restrict__ wsm, float* __restrict__ ctx){
  __shared__ float wloc[512];
  int b = blockIdx.x >> 2, chunk = blockIdx.x & 3;
  int tid = threadIdx.x;
  for(int t = tid; t < 512; t += 256) wloc[t] = wsm[b*512 + t];
  __syncthreads();
  int d = chunk*256 + tid;
  float acc = 0.f;
  #pragma unroll 8
  for(int t = 0; t < 512; t++)
    acc += wloc[t] * bf2f_bits(f_out[(size_t)(t*64 + b)*1024 + d]);
  ctx[b*1024 + d] = acc;
}

// ---------------------------------------------------------------- classifier
__global__ void k_cls1(const float* __restrict__ ctx, const float* __restrict__ w1,
                       const float* __restrict__ b1, float* __restrict__ hid){
  int idx = blockIdx.x*256 + threadIdx.x;   // 32768
  int b = idx >> 9, h = idx & 511;
  float acc = b1[h];
  for(int d = 0; d < 1024; d++) acc += ctx[b*1024 + d] * w1[d*512 + h];
  hid[idx] = fmaxf(acc, 0.f);
}

__global__ void k_cls2(const float* __restrict__ hid, const float* __restrict__ w2,
                       const float* __restrict__ b2, float* __restrict__ out){
  int idx = threadIdx.x;   // 640
  if(idx >= 640) return;
  int b = idx / 10, o = idx % 10;
  float acc = b2[o];
  for(int h = 0; h < 512; h++) acc += hid[b*512 + h] * w2[h*10 + o];
  out[idx] = acc;
}

// ---------------------------------------------------------------- launch
extern "C" void kernel_launch(void* const* d_in, const int* in_sizes, int n_in,
                              void* d_out, int out_size, void* d_ws, size_t ws_size,
                              hipStream_t stream)
{
  const float* emb    = (const float*)d_in[1];
  const float* w_ih_f = (const float*)d_in[2];
  const float* w_hh_f = (const float*)d_in[3];
  const float* b_ih_f = (const float*)d_in[4];
  const float* b_hh_f = (const float*)d_in[5];
  const float* w_ih_b = (const float*)d_in[6];
  const float* w_hh_b = (const float*)d_in[7];
  const float* b_ih_b = (const float*)d_in[8];
  const float* b_hh_b = (const float*)d_in[9];
  const float* attn_w = (const float*)d_in[10];
  const float* attn_b = (const float*)d_in[11];
  const float* ctx_w  = (const float*)d_in[12];
  const float* cls_w1 = (const float*)d_in[13];
  const float* cls_b1 = (const float*)d_in[14];
  const float* cls_w2 = (const float*)d_in[15];
  const float* cls_b2 = (const float*)d_in[16];
  float* out = (float*)d_out;

  char* ws = (char*)d_ws;
  size_t off = 0;
  auto alloc = [&](size_t bytes){ void* p = ws + off; off += (bytes + 255) & ~(size_t)255; return p; };
  uint16_t* femb = (uint16_t*)alloc((size_t)MROWS*DIN*2);      // emb bf16, later overlaid by f_out
  uint16_t* wcat = (uint16_t*)alloc((size_t)NC*DIN*2);
  uint16_t* xp   = (uint16_t*)alloc((size_t)MROWS*NC*2);       // blocked layout
  uint16_t* awT  = (uint16_t*)alloc((size_t)1024*1024*2);
  uint4*    wmem = (uint4*)alloc((size_t)2*16*96*64*16);       // 3 MB pre-swizzled W
  unsigned long long* tagbuf = (unsigned long long*)alloc((size_t)2*2*4*16*256*8);  // 1 MB
  float* scraw   = (float*)alloc((size_t)MROWS*4);
  float* wsm     = (float*)alloc((size_t)B_*T_*4);
  float* ctx     = (float*)alloc((size_t)B_*1024*4);
  float* hid     = (float*)alloc((size_t)B_*512*4);

  hipMemsetAsync(tagbuf, 0, (size_t)2*2*4*16*256*8, stream);
  hipMemsetAsync(scraw, 0, (size_t)MROWS*4, stream);

  k_conv_emb<<<16384, 256, 0, stream>>>(emb, femb, (long)MROWS*DIN/8);
  k_conv_wcat<<<12288, 256, 0, stream>>>(w_ih_f, w_ih_b, wcat, NC*DIN);
  k_conv_awt<<<4096, 256, 0, stream>>>(attn_w, awT, 1024*1024);
  k_conv_whh<<<768, 256, 0, stream>>>(w_hh_f, w_hh_b, wmem);

  k_gemm_xp<<<dim3(24,256), 256, 0, stream>>>(femb, wcat, b_ih_f, b_ih_b, xp);

  k_recur<<<128, 768, 0, stream>>>(xp, wmem, b_hh_f, b_hh_b, tagbuf, femb /* = f_out */);

  k_gemm_att<<<dim3(8,256), 256, 0, stream>>>(femb, awT, attn_b, ctx_w, scraw);
  k_softmax<<<64, 256, 0, stream>>>(scraw, wsm);
  k_ctx<<<256, 256, 0, stream>>>(femb, wsm, ctx);
  k_cls1<<<128, 256, 0, stream>>>(ctx, cls_w1, cls_b1, hid);
  k_cls2<<<1, 640, 0, stream>>>(hid, cls_w2, cls_b2, out);
}

// Round 12
// 1549.149 us; speedup vs baseline: 15.3600x; 1.1103x over previous
//
#include <hip/hip_runtime.h>
#include <stdint.h>

// Problem constants
#define T_   512
#define B_   64
#define DIN  1024
#define HID  512
#define G3   1536     // 3*HID
#define NC   3072     // both dirs of gates
#define MROWS 32768   // T_*B_

typedef __bf16 bf16;
typedef __bf16 bf16x8 __attribute__((ext_vector_type(8)));
typedef float  f32x4  __attribute__((ext_vector_type(4)));

#define GLOBAL_AS __attribute__((address_space(1)))
#define LDS_AS    __attribute__((address_space(3)))

__device__ __forceinline__ uint16_t f2bf_bits(float x){
  union{float f; uint32_t u;} v; v.f = x;
  uint32_t u = v.u;
  u += 0x7FFFu + ((u >> 16) & 1u);   // round-to-nearest-even
  return (uint16_t)(u >> 16);
}
__device__ __forceinline__ float bf2f_bits(uint16_t h){
  union{uint32_t u; float f;} v; v.u = ((uint32_t)h) << 16;
  return v.f;
}
__device__ __forceinline__ float sig_f(float x){
  return 1.f/(1.f + __expf(-x));
}
__device__ __forceinline__ float tanh_f(float x){
  return 1.f - 2.f/(1.f + __expf(2.f*x));
}
__device__ __forceinline__ bf16x8 as_bf16x8(uint4 u){
  union{uint4 a; bf16x8 b;} c; c.a = u; return c.b;
}

// ---------------------------------------------------------------- converts
__global__ void k_conv_emb(const float* __restrict__ src, uint16_t* __restrict__ dst, long n8){
  long i = (long)blockIdx.x*blockDim.x + threadIdx.x;
  if(i >= n8) return;
  const float4* s = (const float4*)src;
  float4 a = s[i*2], b = s[i*2+1];
  uint32_t p0 = (uint32_t)f2bf_bits(a.x) | ((uint32_t)f2bf_bits(a.y) << 16);
  uint32_t p1 = (uint32_t)f2bf_bits(a.z) | ((uint32_t)f2bf_bits(a.w) << 16);
  uint32_t p2 = (uint32_t)f2bf_bits(b.x) | ((uint32_t)f2bf_bits(b.y) << 16);
  uint32_t p3 = (uint32_t)f2bf_bits(b.z) | ((uint32_t)f2bf_bits(b.w) << 16);
  ((uint4*)dst)[i] = make_uint4(p0,p1,p2,p3);
}

__global__ void k_conv_wcat(const float* __restrict__ wf, const float* __restrict__ wb, uint16_t* __restrict__ dst, int n){
  int i = blockIdx.x*256 + threadIdx.x;
  if(i >= n) return;
  float v = (i < G3*DIN) ? wf[i] : wb[i - G3*DIN];
  dst[i] = f2bf_bits(v);
}

__global__ void k_conv_awt(const float* __restrict__ aw, uint16_t* __restrict__ dst, int n){
  int i = blockIdx.x*256 + threadIdx.x;
  if(i >= n) return;
  int e = i >> 10, d = i & 1023;
  dst[i] = f2bf_bits(aw[d*1024 + e]);   // transpose: awT[e][d]
}

// W_hh -> bf16, member-sliced, chunk-XOR-pre-swizzled (same layout as r6-r9).
__global__ void k_conv_whh(const float* __restrict__ wf, const float* __restrict__ wb, uint4* __restrict__ wmem){
  int idx = blockIdx.x*256 + threadIdx.x;   // 196608 total
  if(idx >= 2*16*96*64) return;
  int c  = idx & 63;
  int t2 = idx >> 6;
  int lc = t2 % 96;
  int t3 = t2 / 96;
  int member = t3 & 15, dir = t3 >> 4;
  int ct = lc >> 4, rr = lc & 15;
  int gcol = (ct >> 1)*512 + member*32 + (ct & 1)*16 + rr;
  int csrc = c ^ (lc & 7);
  const float* src = (dir ? wb : wf) + (size_t)gcol*512 + csrc*8;
  float4 f0 = *(const float4*)src;
  float4 f1 = *(const float4*)(src + 4);
  uint32_t p0 = (uint32_t)f2bf_bits(f0.x) | ((uint32_t)f2bf_bits(f0.y) << 16);
  uint32_t p1 = (uint32_t)f2bf_bits(f0.z) | ((uint32_t)f2bf_bits(f0.w) << 16);
  uint32_t p2 = (uint32_t)f2bf_bits(f1.x) | ((uint32_t)f2bf_bits(f1.y) << 16);
  uint32_t p3 = (uint32_t)f2bf_bits(f1.z) | ((uint32_t)f2bf_bits(f1.w) << 16);
  wmem[idx] = make_uint4(p0,p1,p2,p3);
}

// ---------------------------------------------------------------- GEMM: xp = emb @ Wcat^T + bias
// OUTPUT BLOCKED for k_recur: xp[dir][t][bg][member][g][16 rows][32 cols] bf16
__launch_bounds__(256)
__global__ void k_gemm_xp(const uint16_t* __restrict__ A, const uint16_t* __restrict__ Bw,
                          const float* __restrict__ bihf, const float* __restrict__ bihb,
                          uint16_t* __restrict__ C)
{
  __shared__ uint16_t lA[2][128*32];
  __shared__ uint16_t lB[2][128*32];
  const int K = 1024;
  int bn = blockIdx.x, bm = blockIdx.y;
  int tid = threadIdx.x;
  int lane = tid & 63, wid = tid >> 6;
  int wm = wid >> 1, wn = wid & 1;
  int rowBase = bm*128, colBase = bn*128;
  int rg = lane >> 4, rr = lane & 15;

  auto stage = [&](int buf, int kt){
    #pragma unroll
    for(int i=0;i<2;i++){
      int e = (i*256 + tid)*8;
      int r = e >> 5, c = e & 31;
      __builtin_amdgcn_global_load_lds((const GLOBAL_AS void*)(A + (size_t)(rowBase + r)*K + kt*32 + c),
                                       (LDS_AS void*)&lA[buf][e], 16, 0, 0);
    }
    #pragma unroll
    for(int i=0;i<2;i++){
      int e = (i*256 + tid)*8;
      int r = e >> 5, c = e & 31;
      __builtin_amdgcn_global_load_lds((const GLOBAL_AS void*)(Bw + (size_t)(colBase + r)*K + kt*32 + c),
                                       (LDS_AS void*)&lB[buf][e], 16, 0, 0);
    }
  };

  f32x4 acc[4][4];
  #pragma unroll
  for(int mi=0;mi<4;mi++)
    #pragma unroll
    for(int ni=0;ni<4;ni++) acc[mi][ni] = (f32x4){0.f,0.f,0.f,0.f};

  stage(0, 0);
  __syncthreads();
  for(int kt=0; kt<32; kt++){
    int buf = kt & 1;
    if(kt+1 < 32) stage(buf^1, kt+1);
    bf16x8 af[4], bfv[4];
    #pragma unroll
    for(int mi=0;mi<4;mi++)
      af[mi] = *(const bf16x8*)&lA[buf][(wm*64 + mi*16 + rr)*32 + rg*8];
    #pragma unroll
    for(int ni=0;ni<4;ni++)
      bfv[ni] = *(const bf16x8*)&lB[buf][(wn*64 + ni*16 + rr)*32 + rg*8];
    #pragma unroll
    for(int mi=0;mi<4;mi++)
      #pragma unroll
      for(int ni=0;ni<4;ni++)
        acc[mi][ni] = __builtin_amdgcn_mfma_f32_16x16x32_bf16(af[mi], bfv[ni], acc[mi][ni], 0,0,0);
    __syncthreads();
  }

  #pragma unroll
  for(int ni=0;ni<4;ni++){
    int col = colBase + wn*64 + ni*16 + rr;
    float bv = (col < G3) ? bihf[col] : bihb[col - G3];
    int dircol = (col >= G3) ? 1 : 0;
    int cm = col - dircol*G3;
    int g  = cm >> 9;
    int j  = cm & 511;
    int mem = j >> 5, cc = j & 31;
    #pragma unroll
    for(int mi=0;mi<4;mi++){
      int row0 = rowBase + wm*64 + mi*16 + rg*4;
      int tt = row0 >> 6;
      int b0 = row0 & 63;
      int bgx = b0 >> 4, rr0 = b0 & 15;
      size_t ob = (((((size_t)dircol*512 + tt)*4 + bgx)*16 + mem)*3 + g)*512 + rr0*32 + cc;
      C[ob]      = f2bf_bits(acc[mi][ni][0]+bv);
      C[ob+32]   = f2bf_bits(acc[mi][ni][1]+bv);
      C[ob+64]   = f2bf_bits(acc[mi][ni][2]+bv);
      C[ob+96]   = f2bf_bits(acc[mi][ni][3]+bv);
    }
  }
}

// ---------------------------------------------------------------- GEMM: attention, fused tanh + ctx_w dot
__launch_bounds__(256)
__global__ void k_gemm_att(const uint16_t* __restrict__ A, const uint16_t* __restrict__ Bw,
                           const float* __restrict__ attn_b, const float* __restrict__ ctx_w,
                           float* __restrict__ scores_raw)
{
  __shared__ uint16_t lA[2][128*32];
  __shared__ uint16_t lB[2][128*32];
  const int K = 1024;
  int bn = blockIdx.x, bm = blockIdx.y;
  int tid = threadIdx.x;
  int lane = tid & 63, wid = tid >> 6;
  int wm = wid >> 1, wn = wid & 1;
  int rowBase = bm*128, colBase = bn*128;
  int rg = lane >> 4, rr = lane & 15;

  auto stage = [&](int buf, int kt){
    #pragma unroll
    for(int i=0;i<2;i++){
      int e = (i*256 + tid)*8;
      int r = e >> 5, c = e & 31;
      __builtin_amdgcn_global_load_lds((const GLOBAL_AS void*)(A + (size_t)(rowBase + r)*K + kt*32 + c),
                                       (LDS_AS void*)&lA[buf][e], 16, 0, 0);
    }
    #pragma unroll
    for(int i=0;i<2;i++){
      int e = (i*256 + tid)*8;
      int r = e >> 5, c = e & 31;
      __builtin_amdgcn_global_load_lds((const GLOBAL_AS void*)(Bw + (size_t)(colBase + r)*K + kt*32 + c),
                                       (LDS_AS void*)&lB[buf][e], 16, 0, 0);
    }
  };

  f32x4 acc[4][4];
  #pragma unroll
  for(int mi=0;mi<4;mi++)
    #pragma unroll
    for(int ni=0;ni<4;ni++) acc[mi][ni] = (f32x4){0.f,0.f,0.f,0.f};

  stage(0, 0);
  __syncthreads();
  for(int kt=0; kt<32; kt++){
    int buf = kt & 1;
    if(kt+1 < 32) stage(buf^1, kt+1);
    bf16x8 af[4], bfv[4];
    #pragma unroll
    for(int mi=0;mi<4;mi++)
      af[mi] = *(const bf16x8*)&lA[buf][(wm*64 + mi*16 + rr)*32 + rg*8];
    #pragma unroll
    for(int ni=0;ni<4;ni++)
      bfv[ni] = *(const bf16x8*)&lB[buf][(wn*64 + ni*16 + rr)*32 + rg*8];
    #pragma unroll
    for(int mi=0;mi<4;mi++)
      #pragma unroll
      for(int ni=0;ni<4;ni++)
        acc[mi][ni] = __builtin_amdgcn_mfma_f32_16x16x32_bf16(af[mi], bfv[ni], acc[mi][ni], 0,0,0);
    __syncthreads();
  }

  float ab[4], cw[4];
  #pragma unroll
  for(int ni=0;ni<4;ni++){
    int col = colBase + wn*64 + ni*16 + rr;
    ab[ni] = attn_b[col];
    cw[ni] = ctx_w[col];
  }
  #pragma unroll
  for(int mi=0;mi<4;mi++){
    #pragma unroll
    for(int r=0;r<4;r++){
      float part = 0.f;
      #pragma unroll
      for(int ni=0;ni<4;ni++) part += tanhf(acc[mi][ni][r] + ab[ni]) * cw[ni];
      #pragma unroll
      for(int off=1; off<16; off<<=1) part += __shfl_xor(part, off);
      if(rr == 0){
        int row = rowBase + wm*64 + mi*16 + rg*4 + r;
        atomicAdd(&scores_raw[row], part);
      }
    }
  }
}

// ---------------------------------------------------------------- recurrence v10c: tag-in-data + W in registers.
// Wave (ct,kh) keeps its 8 MFMA B-fragments (32 VGPRs/lane) in registers; liveness anchored
// via SCALAR asm operands (vector "v" operands unsupported by backend). No Wl LDS (125->29 KB).
// h transport: r9-proven tagged u64 agent atomics; 2 barriers/step.
__launch_bounds__(768, 3)
__global__ void k_recur(const uint16_t* __restrict__ xp,     // blocked [dir][T][bg][member][3][16][32]
                        const uint4* __restrict__ wmem,      // pre-swizzled W slices
                        const float* __restrict__ bhhf, const float* __restrict__ bhhb,
                        unsigned long long* __restrict__ tagbuf,
                        uint16_t* __restrict__ f_out)
{
  __shared__ uint16_t hl[16*512];        // 16 KB, chunk-XOR swizzled
  __shared__ float    ghl[2*6*16*17];    // 12.75 KB

  int bid = blockIdx.x;
  int dir = bid & 1, bg = (bid >> 1) & 3, member = bid >> 3;
  int jb = member*32;
  int tid = threadIdx.x;
  int lane = tid & 63, w = tid >> 6;
  int rr = lane & 15, rg = lane >> 4;
  int ct = w >> 1, kh = w & 1;

  // ---- W fragments -> registers (8 x 16B per lane, loop-invariant) ----
  // source chunk ch = kh*32 + ks*4 + rg at row lc = ct*16 + rr; stored idx = ch ^ (rr&7)
  const uint4* wsl = wmem + (size_t)(dir*16 + member)*6144 + (ct*16 + rr)*64;
  int xm = rr & 7;
  uint4 wu0 = wsl[(kh*32 +  0 + rg) ^ xm];
  uint4 wu1 = wsl[(kh*32 +  4 + rg) ^ xm];
  uint4 wu2 = wsl[(kh*32 +  8 + rg) ^ xm];
  uint4 wu3 = wsl[(kh*32 + 12 + rg) ^ xm];
  uint4 wu4 = wsl[(kh*32 + 16 + rg) ^ xm];
  uint4 wu5 = wsl[(kh*32 + 20 + rg) ^ xm];
  uint4 wu6 = wsl[(kh*32 + 24 + rg) ^ xm];
  uint4 wu7 = wsl[(kh*32 + 28 + rg) ^ xm];
  asm volatile("" :: "v"(wu0.x), "v"(wu0.y), "v"(wu0.z), "v"(wu0.w),
                     "v"(wu1.x), "v"(wu1.y), "v"(wu1.z), "v"(wu1.w));
  asm volatile("" :: "v"(wu2.x), "v"(wu2.y), "v"(wu2.z), "v"(wu2.w),
                     "v"(wu3.x), "v"(wu3.y), "v"(wu3.z), "v"(wu3.w));
  asm volatile("" :: "v"(wu4.x), "v"(wu4.y), "v"(wu4.z), "v"(wu4.w),
                     "v"(wu5.x), "v"(wu5.y), "v"(wu5.z), "v"(wu5.w));
  asm volatile("" :: "v"(wu6.x), "v"(wu6.y), "v"(wu6.z), "v"(wu6.w),
                     "v"(wu7.x), "v"(wu7.y), "v"(wu7.z), "v"(wu7.w));

  for(int i = tid; i < 2*6*16*17; i += 768) ghl[i] = 0.f;

  // gate-thread constants: thread (tid<512) owns (row=tid>>5, col=jb+(tid&31))
  int gcol = tid & 31;
  const float* bhh = dir ? bhhb : bhhf;
  float bR = 0.f, bZ = 0.f, bN = 0.f, hprev = 0.f;
  if(tid < 512){
    bR = bhh[jb + gcol];
    bZ = bhh[512 + jb + gcol];
    bN = bhh[1024 + jb + gcol];
  }

  // consumer staging role (tid<512): row, 8 slots (stride 32)
  int srow = tid >> 5;
  int sbase = tid & 31;                   // slot base; slots sbase+32k
  int cswz = ((sbase >> 2) ^ (srow & 7)); // swizzled chunk base
  int lpos0 = srow*512 + cswz*8 + (sbase & 3)*2;

  __syncthreads();   // ghl zeroed

  #pragma unroll 1
  for(int t = 0; t < 512; t++){
    int trow = dir ? (511 - t) : t;

    // xp loads: 3 coalesced 1KB loads (blocked layout); consumed in gate phase
    uint16_t xr16 = 0, xz16 = 0, xn16 = 0;
    if(tid < 512){
      const uint16_t* xb = xp + (((((size_t)dir*512 + trow)*4 + bg)*16 + member)*3)*512;
      xr16 = xb[tid];
      xz16 = xb[512 + tid];
      xn16 = xb[1024 + tid];
    }

    if(t > 0 && tid < 512){
      // tagged h load: 8 slots, retry until tag == t
      const unsigned long long* tb =
        tagbuf + ((size_t)((dir*2 + ((t-1) & 1))*4 + bg)*16 + srow)*256 + sbase;
      unsigned want = (unsigned)t;
      unsigned long long v0,v1,v2,v3,v4,v5,v6,v7;
      v0 = __hip_atomic_load(tb +   0, __ATOMIC_RELAXED, __HIP_MEMORY_SCOPE_AGENT);
      v1 = __hip_atomic_load(tb +  32, __ATOMIC_RELAXED, __HIP_MEMORY_SCOPE_AGENT);
      v2 = __hip_atomic_load(tb +  64, __ATOMIC_RELAXED, __HIP_MEMORY_SCOPE_AGENT);
      v3 = __hip_atomic_load(tb +  96, __ATOMIC_RELAXED, __HIP_MEMORY_SCOPE_AGENT);
      v4 = __hip_atomic_load(tb + 128, __ATOMIC_RELAXED, __HIP_MEMORY_SCOPE_AGENT);
      v5 = __hip_atomic_load(tb + 160, __ATOMIC_RELAXED, __HIP_MEMORY_SCOPE_AGENT);
      v6 = __hip_atomic_load(tb + 192, __ATOMIC_RELAXED, __HIP_MEMORY_SCOPE_AGENT);
      v7 = __hip_atomic_load(tb + 224, __ATOMIC_RELAXED, __HIP_MEMORY_SCOPE_AGENT);
      bool o0 = ((unsigned)v0 == want), o1 = ((unsigned)v1 == want);
      bool o2 = ((unsigned)v2 == want), o3 = ((unsigned)v3 == want);
      bool o4 = ((unsigned)v4 == want), o5 = ((unsigned)v5 == want);
      bool o6 = ((unsigned)v6 == want), o7 = ((unsigned)v7 == want);
      while(!(o0 & o1 & o2 & o3 & o4 & o5 & o6 & o7)){
        if(!o0){ v0 = __hip_atomic_load(tb +   0, __ATOMIC_RELAXED, __HIP_MEMORY_SCOPE_AGENT); o0 = ((unsigned)v0 == want); }
        if(!o1){ v1 = __hip_atomic_load(tb +  32, __ATOMIC_RELAXED, __HIP_MEMORY_SCOPE_AGENT); o1 = ((unsigned)v1 == want); }
        if(!o2){ v2 = __hip_atomic_load(tb +  64, __ATOMIC_RELAXED, __HIP_MEMORY_SCOPE_AGENT); o2 = ((unsigned)v2 == want); }
        if(!o3){ v3 = __hip_atomic_load(tb +  96, __ATOMIC_RELAXED, __HIP_MEMORY_SCOPE_AGENT); o3 = ((unsigned)v3 == want); }
        if(!o4){ v4 = __hip_atomic_load(tb + 128, __ATOMIC_RELAXED, __HIP_MEMORY_SCOPE_AGENT); o4 = ((unsigned)v4 == want); }
        if(!o5){ v5 = __hip_atomic_load(tb + 160, __ATOMIC_RELAXED, __HIP_MEMORY_SCOPE_AGENT); o5 = ((unsigned)v5 == want); }
        if(!o6){ v6 = __hip_atomic_load(tb + 192, __ATOMIC_RELAXED, __HIP_MEMORY_SCOPE_AGENT); o6 = ((unsigned)v6 == want); }
        if(!o7){ v7 = __hip_atomic_load(tb + 224, __ATOMIC_RELAXED, __HIP_MEMORY_SCOPE_AGENT); o7 = ((unsigned)v7 == want); }
      }
      // LDS stage (chunk-XOR swizzled); slot s=sbase+32k -> chunk (cswz + 8k)
      *(uint32_t*)&hl[lpos0 +   0] = (uint32_t)(v0 >> 32);
      *(uint32_t*)&hl[lpos0 +  64] = (uint32_t)(v1 >> 32);
      *(uint32_t*)&hl[lpos0 + 128] = (uint32_t)(v2 >> 32);
      *(uint32_t*)&hl[lpos0 + 192] = (uint32_t)(v3 >> 32);
      *(uint32_t*)&hl[lpos0 + 256] = (uint32_t)(v4 >> 32);
      *(uint32_t*)&hl[lpos0 + 320] = (uint32_t)(v5 >> 32);
      *(uint32_t*)&hl[lpos0 + 384] = (uint32_t)(v6 >> 32);
      *(uint32_t*)&hl[lpos0 + 448] = (uint32_t)(v7 >> 32);
    }
    __syncthreads();   // (A) hl ready

    if(t > 0){
      // gh partial: wave (ct, kh): 16 rows x 16 cols over K-half kh, W from registers
      f32x4 acc = (f32x4){0.f,0.f,0.f,0.f};
      {
        bf16x8 a0 = *(const bf16x8*)&hl[rr*512 + (((kh*32 +  0 + rg)) ^ xm)*8];
        acc = __builtin_amdgcn_mfma_f32_16x16x32_bf16(a0, as_bf16x8(wu0), acc, 0,0,0);
        bf16x8 a1 = *(const bf16x8*)&hl[rr*512 + (((kh*32 +  4 + rg)) ^ xm)*8];
        acc = __builtin_amdgcn_mfma_f32_16x16x32_bf16(a1, as_bf16x8(wu1), acc, 0,0,0);
        bf16x8 a2 = *(const bf16x8*)&hl[rr*512 + (((kh*32 +  8 + rg)) ^ xm)*8];
        acc = __builtin_amdgcn_mfma_f32_16x16x32_bf16(a2, as_bf16x8(wu2), acc, 0,0,0);
        bf16x8 a3 = *(const bf16x8*)&hl[rr*512 + (((kh*32 + 12 + rg)) ^ xm)*8];
        acc = __builtin_amdgcn_mfma_f32_16x16x32_bf16(a3, as_bf16x8(wu3), acc, 0,0,0);
        bf16x8 a4 = *(const bf16x8*)&hl[rr*512 + (((kh*32 + 16 + rg)) ^ xm)*8];
        acc = __builtin_amdgcn_mfma_f32_16x16x32_bf16(a4, as_bf16x8(wu4), acc, 0,0,0);
        bf16x8 a5 = *(const bf16x8*)&hl[rr*512 + (((kh*32 + 20 + rg)) ^ xm)*8];
        acc = __builtin_amdgcn_mfma_f32_16x16x32_bf16(a5, as_bf16x8(wu5), acc, 0,0,0);
        bf16x8 a6 = *(const bf16x8*)&hl[rr*512 + (((kh*32 + 24 + rg)) ^ xm)*8];
        acc = __builtin_amdgcn_mfma_f32_16x16x32_bf16(a6, as_bf16x8(wu6), acc, 0,0,0);
        bf16x8 a7 = *(const bf16x8*)&hl[rr*512 + (((kh*32 + 28 + rg)) ^ xm)*8];
        acc = __builtin_amdgcn_mfma_f32_16x16x32_bf16(a7, as_bf16x8(wu7), acc, 0,0,0);
      }
      #pragma unroll
      for(int j = 0; j < 4; j++)
        ghl[((kh*6 + ct)*16 + rg*4 + j)*17 + rr] = acc[j];
    }
    __syncthreads();   // (B) ghl ready (zeros at t==0)

    // gates + tagged publish
    if(tid < 512){
      int grow = tid >> 5;
      int c16 = gcol >> 4, cc = gcol & 15;
      float gR = ghl[((0 + c16)*16 + grow)*17 + cc] + ghl[((6  + c16)*16 + grow)*17 + cc] + bR;
      float gZ = ghl[((2 + c16)*16 + grow)*17 + cc] + ghl[((8  + c16)*16 + grow)*17 + cc] + bZ;
      float gN = ghl[((4 + c16)*16 + grow)*17 + cc] + ghl[((10 + c16)*16 + grow)*17 + cc] + bN;
      float rv = sig_f(bf2f_bits(xr16) + gR);
      float zv = sig_f(bf2f_bits(xz16) + gZ);
      float nv = tanh_f(bf2f_bits(xn16) + rv*gN);
      float hnew = (1.f - zv)*nv + zv*hprev;
      hprev = hnew;
      unsigned hb = (unsigned)f2bf_bits(hnew);
      unsigned nb = (unsigned)__shfl_down((int)hb, 1);
      if((tid & 1) == 0){
        unsigned pk = hb | (nb << 16);
        int slot = member*16 + (gcol >> 1);
        unsigned long long pv = ((unsigned long long)pk << 32) | (unsigned)(t + 1);
        __hip_atomic_store(
          tagbuf + ((size_t)((dir*2 + (t & 1))*4 + bg)*16 + grow)*256 + slot,
          pv, __ATOMIC_RELAXED, __HIP_MEMORY_SCOPE_AGENT);
        *(unsigned*)&f_out[((size_t)trow*64 + bg*16 + grow)*1024 + dir*512 + jb + gcol] = pk;
      }
    }
    // no drain barrier: tag carries sync; next iteration's barriers cover LDS hazards
  }
}

// ---------------------------------------------------------------- softmax over T per batch
__global__ void k_softmax(const float* __restrict__ scores_raw, float* __restrict__ wsm){
  __shared__ float sv[512];
  __shared__ float red[8];
  int b = blockIdx.x;
  int tid = threadIdx.x;
  float mymax = -1e30f;
  for(int t = tid; t < 512; t += 256){
    float s = tanhf(scores_raw[t*64 + b]);
    sv[t] = s;
    mymax = fmaxf(mymax, s);
  }
  #pragma unroll
  for(int off=1; off<64; off<<=1) mymax = fmaxf(mymax, __shfl_xor(mymax, off));
  if((tid&63)==0) red[tid>>6] = mymax;
  __syncthreads();
  float bmax = fmaxf(fmaxf(red[0],red[1]), fmaxf(red[2],red[3]));
  __syncthreads();
  float mysum = 0.f;
  for(int t = tid; t < 512; t += 256){
    float e = __expf(sv[t] - bmax);
    sv[t] = e;
    mysum += e;
  }
  #pragma unroll
  for(int off=1; off<64; off<<=1) mysum += __shfl_xor(mysum, off);
  if((tid&63)==0) red[tid>>6] = mysum;
  __syncthreads();
  float inv = 1.f/(red[0]+red[1]+red[2]+red[3]);
  for(int t = tid; t < 512; t += 256) wsm[b*512 + t] = sv[t]*inv;
}

// ---------------------------------------------------------------- ctx[b,d] = sum_t w[b,t] f[t,b,d]
__global__ void k_ctx(const uint16_t* __restrict__ f_out, const float* __restrict__ wsm, float* __restrict__ ctx){
  __shared__ float wloc[512];
  int b = blockIdx.x >> 2, chunk = blockIdx.x & 3;
  int tid = threadIdx.x;
  for(int t = tid; t < 512; t += 256) wloc[t] = wsm[b*512 + t];
  __syncthreads();
  int d = chunk*256 + tid;
  float acc = 0.f;
  #pragma unroll 8
  for(int t = 0; t < 512; t++)
    acc += wloc[t] * bf2f_bits(f_out[(size_t)(t*64 + b)*1024 + d]);
  ctx[b*1024 + d] = acc;
}

// ---------------------------------------------------------------- classifier
__global__ void k_cls1(const float* __restrict__ ctx, const float* __restrict__ w1,
                       const float* __restrict__ b1, float* __restrict__ hid){
  int idx = blockIdx.x*256 + threadIdx.x;   // 32768
  int b = idx >> 9, h = idx & 511;
  float acc = b1[h];
  for(int d = 0; d < 1024; d++) acc += ctx[b*1024 + d] * w1[d*512 + h];
  hid[idx] = fmaxf(acc, 0.f);
}

__global__ void k_cls2(const float* __restrict__ hid, const float* __restrict__ w2,
                       const float* __restrict__ b2, float* __restrict__ out){
  int idx = threadIdx.x;   // 640
  if(idx >= 640) return;
  int b = idx / 10, o = idx % 10;
  float acc = b2[o];
  for(int h = 0; h < 512; h++) acc += hid[b*512 + h] * w2[h*10 + o];
  out[idx] = acc;
}

// ---------------------------------------------------------------- launch
extern "C" void kernel_launch(void* const* d_in, const int* in_sizes, int n_in,
                              void* d_out, int out_size, void* d_ws, size_t ws_size,
                              hipStream_t stream)
{
  const float* emb    = (const float*)d_in[1];
  const float* w_ih_f = (const float*)d_in[2];
  const float* w_hh_f = (const float*)d_in[3];
  const float* b_ih_f = (const float*)d_in[4];
  const float* b_hh_f = (const float*)d_in[5];
  const float* w_ih_b = (const float*)d_in[6];
  const float* w_hh_b = (const float*)d_in[7];
  const float* b_ih_b = (const float*)d_in[8];
  const float* b_hh_b = (const float*)d_in[9];
  const float* attn_w = (const float*)d_in[10];
  const float* attn_b = (const float*)d_in[11];
  const float* ctx_w  = (const float*)d_in[12];
  const float* cls_w1 = (const float*)d_in[13];
  const float* cls_b1 = (const float*)d_in[14];
  const float* cls_w2 = (const float*)d_in[15];
  const float* cls_b2 = (const float*)d_in[16];
  float* out = (float*)d_out;

  char* ws = (char*)d_ws;
  size_t off = 0;
  auto alloc = [&](size_t bytes){ void* p = ws + off; off += (bytes + 255) & ~(size_t)255; return p; };
  uint16_t* femb = (uint16_t*)alloc((size_t)MROWS*DIN*2);      // emb bf16, later overlaid by f_out
  uint16_t* wcat = (uint16_t*)alloc((size_t)NC*DIN*2);
  uint16_t* xp   = (uint16_t*)alloc((size_t)MROWS*NC*2);       // blocked layout
  uint16_t* awT  = (uint16_t*)alloc((size_t)1024*1024*2);
  uint4*    wmem = (uint4*)alloc((size_t)2*16*96*64*16);       // 3 MB pre-swizzled W
  unsigned long long* tagbuf = (unsigned long long*)alloc((size_t)2*2*4*16*256*8);  // 1 MB
  float* scraw   = (float*)alloc((size_t)MROWS*4);
  float* wsm     = (float*)alloc((size_t)B_*T_*4);
  float* ctx     = (float*)alloc((size_t)B_*1024*4);
  float* hid     = (float*)alloc((size_t)B_*512*4);

  (void)hipMemsetAsync(tagbuf, 0, (size_t)2*2*4*16*256*8, stream);
  (void)hipMemsetAsync(scraw, 0, (size_t)MROWS*4, stream);

  k_conv_emb<<<16384, 256, 0, stream>>>(emb, femb, (long)MROWS*DIN/8);
  k_conv_wcat<<<12288, 256, 0, stream>>>(w_ih_f, w_ih_b, wcat, NC*DIN);
  k_conv_awt<<<4096, 256, 0, stream>>>(attn_w, awT, 1024*1024);
  k_conv_whh<<<768, 256, 0, stream>>>(w_hh_f, w_hh_b, wmem);

  k_gemm_xp<<<dim3(24,256), 256, 0, stream>>>(femb, wcat, b_ih_f, b_ih_b, xp);

  k_recur<<<128, 768, 0, stream>>>(xp, wmem, b_hh_f, b_hh_b, tagbuf, femb /* = f_out */);

  k_gemm_att<<<dim3(8,256), 256, 0, stream>>>(femb, awT, attn_b, ctx_w, scraw);
  k_softmax<<<64, 256, 0, stream>>>(scraw, wsm);
  k_ctx<<<256, 256, 0, stream>>>(femb, wsm, ctx);
  k_cls1<<<128, 256, 0, stream>>>(ctx, cls_w1, cls_b1, hid);
  k_cls2<<<1, 640, 0, stream>>>(hid, cls_w2, cls_b2, out);
}